// Round 1
// baseline (1385.704 us; speedup 1.0000x reference)
//
#include <hip/hip_runtime.h>
#include <stdint.h>

typedef unsigned long long ull;

#define B   64
#define C   768
#define HW  576
#define K   50
#define NLOC (B*K)          // 3200

// ---- workspace layout (bytes) ----
#define OFF_SLOTS   0            // 64 floats
#define OFF_COLSUM  256          // 6*768 floats = 18432
#define OFF_NORM1   18688        // 64*576 floats = 147456
#define OFF_NORM2   166144       // 147456
#define OFF_NN1     313600       // 64*576 ull = 294912
#define OFF_NN2     608512       // 294912
#define OFF_SELP    903424       // 2*64*50 int = 25600
#define OFF_SELQ    929024       // 25600
#define OFF_XG      954624       // 4*3200*768 floats = 39321600
#define OFF_M       40276224     // 6*768*768 floats = 14155776
// total 54432000

// slot indices
#define SLOT_INVG 0
#define SLOT_STD  1   // +mat (0..5)
#define SLOT_COV  7   // +mat (0..5)
#define SLOT_INV1 13
#define SLOT_INV2 14

__device__ __forceinline__ ull umin64(ull a, ull b) { return a < b ? a : b; }

__device__ __forceinline__ float blk_reduce_sum(float v, float* s4) {
    // 256-thread block: wave reduce then 4-partial sum by thread 0
    for (int off = 32; off > 0; off >>= 1) v += __shfl_down(v, off, 64);
    int lane = threadIdx.x & 63, w = threadIdx.x >> 6;
    if (lane == 0) s4[w] = v;
    __syncthreads();
    float r = 0.f;
    if (threadIdx.x == 0) r = s4[0] + s4[1] + s4[2] + s4[3];
    return r; // valid on thread 0 only
}

// ---------------- norms: norm[which][b][p] = sum_c x[b,c,p]^2 ----------------
__global__ __launch_bounds__(576) void norm_kernel(const float* __restrict__ x1,
                                                   const float* __restrict__ x2,
                                                   float* __restrict__ norm) {
    int which = blockIdx.z;
    const float* X = which ? x2 : x1;
    float* out = norm + (size_t)which * (B * HW);
    int b = blockIdx.y;
    int c0 = blockIdx.x * 128;
    int p = threadIdx.x;
    const float* base = X + (size_t)b * C * HW + (size_t)c0 * HW + p;
    float a0 = 0, a1 = 0, a2 = 0, a3 = 0;
    for (int cc = 0; cc < 128; cc += 4) {
        float v0 = base[(cc + 0) * HW];
        float v1 = base[(cc + 1) * HW];
        float v2 = base[(cc + 2) * HW];
        float v3 = base[(cc + 3) * HW];
        a0 = fmaf(v0, v0, a0); a1 = fmaf(v1, v1, a1);
        a2 = fmaf(v2, v2, a2); a3 = fmaf(v3, v3, a3);
    }
    atomicAdd(&out[b * HW + p], (a0 + a1) + (a2 + a3));
}

// ------------- cdist tile + NN mins (row & col) via packed atomicMin -------------
// grid (9 qtiles, 9 ptiles, 64 batches), block 256 = 16x16, 4x4 micro-tile
__global__ __launch_bounds__(256) void cdist_nn(const float* __restrict__ x1,
                                                const float* __restrict__ x2,
                                                const float* __restrict__ norm,
                                                ull* __restrict__ nn1,
                                                ull* __restrict__ nn2) {
    int qt = blockIdx.x, pt = blockIdx.y, b = blockIdx.z;
    const float* X1 = x1 + (size_t)b * C * HW;
    const float* X2 = x2 + (size_t)b * C * HW;
    const float* n1g = norm + b * HW;
    const float* n2g = norm + B * HW + b * HW;

    __shared__ float As[16][64];
    __shared__ float Bs[16][64];
    __shared__ ull rk[64][17];
    __shared__ ull ck[64][17];

    int tid = threadIdx.x;
    int tx = tid & 15, ty = tid >> 4;
    int lr = tid >> 4, lc = (tid & 15) * 4;

    float acc[4][4] = {};
    const float* pa = X1 + (size_t)lr * HW + pt * 64 + lc;
    const float* pb = X2 + (size_t)lr * HW + qt * 64 + lc;

    for (int k0 = 0; k0 < C; k0 += 16) {
        float4 av = *(const float4*)(pa + (size_t)k0 * HW);
        float4 bv = *(const float4*)(pb + (size_t)k0 * HW);
        __syncthreads();
        *(float4*)&As[lr][lc] = av;
        *(float4*)&Bs[lr][lc] = bv;
        __syncthreads();
#pragma unroll
        for (int kk = 0; kk < 16; ++kk) {
            float4 af = *(const float4*)&As[kk][ty * 4];
            float4 bf = *(const float4*)&Bs[kk][tx * 4];
            float a[4] = {af.x, af.y, af.z, af.w};
            float bb[4] = {bf.x, bf.y, bf.z, bf.w};
#pragma unroll
            for (int i = 0; i < 4; ++i)
#pragma unroll
                for (int j = 0; j < 4; ++j)
                    acc[i][j] = fmaf(a[i], bb[j], acc[i][j]);
        }
    }

    // finalize d2 = n1 + n2 - 2G, clamp >= +0, pack, local min
    float n1v[4], n2v[4];
#pragma unroll
    for (int i = 0; i < 4; ++i) n1v[i] = n1g[pt * 64 + ty * 4 + i];
#pragma unroll
    for (int j = 0; j < 4; ++j) n2v[j] = n2g[qt * 64 + tx * 4 + j];

    ull rbest[4] = {~0ull, ~0ull, ~0ull, ~0ull};
    ull cbest[4] = {~0ull, ~0ull, ~0ull, ~0ull};
#pragma unroll
    for (int i = 0; i < 4; ++i) {
#pragma unroll
        for (int j = 0; j < 4; ++j) {
            float d2 = n1v[i] + n2v[j] - 2.0f * acc[i][j];
            d2 = (d2 > 0.0f) ? d2 : 0.0f;
            ull dbits = (ull)__float_as_uint(d2) << 32;
            int p = pt * 64 + ty * 4 + i;
            int q = qt * 64 + tx * 4 + j;
            rbest[i] = umin64(rbest[i], dbits | (unsigned)q);
            cbest[j] = umin64(cbest[j], dbits | (unsigned)p);
        }
    }
#pragma unroll
    for (int i = 0; i < 4; ++i) rk[ty * 4 + i][tx] = rbest[i];
#pragma unroll
    for (int j = 0; j < 4; ++j) ck[tx * 4 + j][ty] = cbest[j];
    __syncthreads();

    if (tid < 64) {
        ull m = ~0ull;
#pragma unroll
        for (int x = 0; x < 16; ++x) m = umin64(m, rk[tid][x]);
        atomicMin(&nn1[b * HW + pt * 64 + tid], m);
    } else if (tid < 128) {
        int q = tid - 64;
        ull m = ~0ull;
#pragma unroll
        for (int y = 0; y < 16; ++y) m = umin64(m, ck[q][y]);
        atomicMin(&nn2[b * HW + qt * 64 + q], m);
    }
}

// ---------------- top-k (k=50 smallest) per (batch, direction) ----------------
__global__ __launch_bounds__(256) void select_topk(const ull* __restrict__ nn1,
                                                   const ull* __restrict__ nn2,
                                                   int* __restrict__ sel_p,
                                                   int* __restrict__ sel_q) {
    int b = blockIdx.x, dir = blockIdx.y;
    const ull* nn = dir ? nn2 : nn1;
    __shared__ ull skey[HW];
    __shared__ unsigned sq[HW];
    __shared__ ull red[256];
    int tid = threadIdx.x;
    for (int p = tid; p < HW; p += 256) {
        ull k = nn[b * HW + p];
        skey[p] = (k & 0xFFFFFFFF00000000ull) | (unsigned)p;
        sq[p] = (unsigned)(k & 0xFFFFFFFFu);
    }
    __syncthreads();
    for (int it = 0; it < K; ++it) {
        ull m = ~0ull;
        for (int p = tid; p < HW; p += 256) m = umin64(m, skey[p]);
        red[tid] = m;
        __syncthreads();
        for (int s = 128; s > 0; s >>= 1) {
            if (tid < s) red[tid] = umin64(red[tid], red[tid + s]);
            __syncthreads();
        }
        if (tid == 0) {
            unsigned pstar = (unsigned)(red[0] & 0xFFFFFFFFu);
            sel_p[(dir * B + b) * K + it] = (int)pstar;
            sel_q[(dir * B + b) * K + it] = (int)sq[pstar];
            skey[pstar] = ~0ull;
        }
        __syncthreads();
    }
}

// ---------------- gather filtered maps into Xg[s][i][c] ----------------
// s: 0=dir0-in(x1,sel_p) 1=dir0-nn(x2,sel_q) 2=dir1-in(x2,sel_p) 3=dir1-nn(x1,sel_q)
__global__ __launch_bounds__(256) void gather_kernel(const float* __restrict__ x1,
                                                     const float* __restrict__ x2,
                                                     const int* __restrict__ sel_p,
                                                     const int* __restrict__ sel_q,
                                                     float* __restrict__ Xg) {
    int i = blockIdx.x;           // 0..3199
    int s = blockIdx.y;           // 0..3
    int b = i / K, j = i % K;
    int dir = s >> 1;
    bool use_q = (s & 1);
    const float* src = (s == 0 || s == 3) ? x1 : x2;
    int idx = (use_q ? sel_q : sel_p)[(dir * B + b) * K + j];
    const float* base = src + (size_t)b * C * HW + idx;
    float* out = Xg + (size_t)s * NLOC * C + (size_t)i * C;
    for (int c = threadIdx.x; c < C; c += 256)
        out[c] = base[(size_t)c * HW];
}

// ---------------- M = X^T X for 6 matrices ----------------
// mats 0..3: Xg (n=3200); 4: pooled_1; 5: pooled_2 (n=64)
__global__ __launch_bounds__(256) void ata_kernel(const float* __restrict__ Xg,
                                                  const float* __restrict__ p1,
                                                  const float* __restrict__ p2,
                                                  float* __restrict__ M) {
    int mat = blockIdx.z;
    const float* X;
    int n;
    if (mat < 4) { X = Xg + (size_t)mat * NLOC * C; n = NLOC; }
    else { X = (mat == 4) ? p1 : p2; n = B; }
    float* Mo = M + (size_t)mat * C * C;
    int ct = blockIdx.x, rt = blockIdx.y;

    __shared__ float As[16][64];
    __shared__ float Bs[16][64];
    int tid = threadIdx.x;
    int tx = tid & 15, ty = tid >> 4;
    int lr = tid >> 4, lc = (tid & 15) * 4;

    float acc[4][4] = {};
    for (int k0 = 0; k0 < n; k0 += 16) {
        float4 av = *(const float4*)&X[(size_t)(k0 + lr) * C + rt * 64 + lc];
        float4 bv = *(const float4*)&X[(size_t)(k0 + lr) * C + ct * 64 + lc];
        __syncthreads();
        *(float4*)&As[lr][lc] = av;
        *(float4*)&Bs[lr][lc] = bv;
        __syncthreads();
#pragma unroll
        for (int kk = 0; kk < 16; ++kk) {
            float4 af = *(const float4*)&As[kk][ty * 4];
            float4 bf = *(const float4*)&Bs[kk][tx * 4];
            float a[4] = {af.x, af.y, af.z, af.w};
            float bb[4] = {bf.x, bf.y, bf.z, bf.w};
#pragma unroll
            for (int i = 0; i < 4; ++i)
#pragma unroll
                for (int j = 0; j < 4; ++j)
                    acc[i][j] = fmaf(a[i], bb[j], acc[i][j]);
        }
    }
#pragma unroll
    for (int i = 0; i < 4; ++i) {
        float4 o = {acc[i][0], acc[i][1], acc[i][2], acc[i][3]};
        *(float4*)&Mo[(size_t)(rt * 64 + ty * 4 + i) * C + ct * 64 + tx * 4] = o;
    }
}

// ---------------- column sums for 6 matrices ----------------
__global__ __launch_bounds__(256) void colsum_kernel(const float* __restrict__ Xg,
                                                     const float* __restrict__ p1,
                                                     const float* __restrict__ p2,
                                                     float* __restrict__ colsum) {
    int mat = blockIdx.z;
    const float* X;
    int n;
    if (mat < 4) { X = Xg + (size_t)mat * NLOC * C; n = NLOC; }
    else { X = (mat == 4) ? p1 : p2; n = B; }
    int c = blockIdx.x * 256 + threadIdx.x;
    if (c >= C) return;
    int chunk = (n + 31) / 32;
    int r0 = blockIdx.y * chunk;
    int r1 = min(n, r0 + chunk);
    float s = 0.f;
    for (int r = r0; r < r1; ++r) s += X[(size_t)r * C + c];
    atomicAdd(&colsum[mat * C + c], s);
}

// ---------------- std term: sum_c relu(1 - sqrt(var_c + eps)) ----------------
__global__ __launch_bounds__(256) void std_kernel(const float* __restrict__ M,
                                                  const float* __restrict__ colsum,
                                                  float* __restrict__ slots) {
    int mat = blockIdx.y;
    float n = (mat < 4) ? (float)NLOC : (float)B;
    int c = blockIdx.x * 256 + threadIdx.x;
    float r = 0.f;
    if (c < C) {
        float mcc = M[(size_t)mat * C * C + (size_t)c * C + c];
        float cs = colsum[mat * C + c];
        float var = (mcc - cs * cs / n) / (n - 1.0f);
        float sd = sqrtf(var + 1e-5f);
        float g = 1.0f - sd;
        r = g > 0.f ? g : 0.f;
    }
    __shared__ float s4[4];
    float t = blk_reduce_sum(r, s4);
    if (threadIdx.x == 0) atomicAdd(&slots[SLOT_STD + mat], t);
}

// ---------------- cov term: sum_{i!=j} cov_ij^2 ----------------
__global__ __launch_bounds__(256) void cov_kernel(const float* __restrict__ M,
                                                  const float* __restrict__ colsum,
                                                  float* __restrict__ slots) {
    int mat = blockIdx.y;
    float n = (mat < 4) ? (float)NLOC : (float)B;
    int idx = blockIdx.x * 256 + threadIdx.x;
    float r = 0.f;
    if (idx < C * C) {
        int i = idx / C, j = idx % C;
        if (i != j) {
            float m = M[(size_t)mat * C * C + idx];
            float cv = (m - colsum[mat * C + i] * colsum[mat * C + j] / n) / (n - 1.0f);
            r = cv * cv;
        }
    }
    __shared__ float s4[4];
    float t = blk_reduce_sum(r, s4);
    if (threadIdx.x == 0) atomicAdd(&slots[SLOT_COV + mat], t);
}

// ---------------- invariance terms ----------------
__global__ __launch_bounds__(256) void inv_global_kernel(const float* __restrict__ p1,
                                                         const float* __restrict__ p2,
                                                         float* __restrict__ slots) {
    int idx = blockIdx.x * 256 + threadIdx.x;
    int stride = gridDim.x * 256;
    float s = 0.f;
    for (int i = idx; i < B * C; i += stride) {
        float d = p1[i] - p2[i];
        s = fmaf(d, d, s);
    }
    __shared__ float s4[4];
    float t = blk_reduce_sum(s, s4);
    if (threadIdx.x == 0) atomicAdd(&slots[SLOT_INVG], t);
}

__global__ __launch_bounds__(256) void inv_local_kernel(const float* __restrict__ Xg,
                                                        float* __restrict__ slots) {
    int pair = blockIdx.y;
    const float* A = Xg + (size_t)(2 * pair) * NLOC * C;
    const float* Bx = A + (size_t)NLOC * C;
    int idx = blockIdx.x * 256 + threadIdx.x;
    int stride = gridDim.x * 256;
    float s = 0.f;
    for (int i = idx; i < NLOC * C; i += stride) {
        float d = A[i] - Bx[i];
        s = fmaf(d, d, s);
    }
    __shared__ float s4[4];
    float t = blk_reduce_sum(s, s4);
    if (threadIdx.x == 0) atomicAdd(&slots[(pair == 0) ? SLOT_INV1 : SLOT_INV2], t);
}

// ---------------- final combine ----------------
__global__ void final_kernel(const float* __restrict__ slots, float* __restrict__ out) {
    float std_t[6], cov_t[6];
    for (int m = 0; m < 6; ++m) {
        std_t[m] = slots[SLOT_STD + m] / (float)C * 0.5f;
        cov_t[m] = slots[SLOT_COV + m] / (float)C;
    }
    float inv_g = slots[SLOT_INVG] / (float)(B * C);
    float global_loss = 25.0f * inv_g + 25.0f * (std_t[4] + std_t[5]) + (cov_t[4] + cov_t[5]);
    float inv1 = 25.0f * slots[SLOT_INV1] / (float)(NLOC * C);
    float inv2 = 25.0f * slots[SLOT_INV2] / (float)(NLOC * C);
    float var1 = 25.0f * (std_t[0] + std_t[1]);
    float var2 = 25.0f * (std_t[2] + std_t[3]);
    float cov1 = cov_t[0] + cov_t[1];
    float cov2 = cov_t[2] + cov_t[3];
    float local_loss = (inv1 + inv2) * 0.5f + (var1 + var2) * 0.5f + (cov1 + cov2) * 0.5f;
    out[0] = 0.5f * global_loss + 0.5f * local_loss;
}

extern "C" void kernel_launch(void* const* d_in, const int* in_sizes, int n_in,
                              void* d_out, int out_size, void* d_ws, size_t ws_size,
                              hipStream_t stream) {
    const float* spatial_1 = (const float*)d_in[0];
    const float* pooled_1  = (const float*)d_in[1];
    const float* spatial_2 = (const float*)d_in[2];
    const float* pooled_2  = (const float*)d_in[3];
    float* out = (float*)d_out;

    char* ws = (char*)d_ws;
    float* slots  = (float*)(ws + OFF_SLOTS);
    float* colsum = (float*)(ws + OFF_COLSUM);
    float* norm   = (float*)(ws + OFF_NORM1);
    ull*   nn1    = (ull*)(ws + OFF_NN1);
    ull*   nn2    = (ull*)(ws + OFF_NN2);
    int*   sel_p  = (int*)(ws + OFF_SELP);
    int*   sel_q  = (int*)(ws + OFF_SELQ);
    float* Xg     = (float*)(ws + OFF_XG);
    float* M      = (float*)(ws + OFF_M);

    // zero slots+colsum+norms; 0xFF the nn key buffers
    hipMemsetAsync(ws, 0, OFF_NN1, stream);
    hipMemsetAsync(ws + OFF_NN1, 0xFF, OFF_SELP - OFF_NN1, stream);

    norm_kernel<<<dim3(6, B, 2), 576, 0, stream>>>(spatial_1, spatial_2, norm);
    cdist_nn<<<dim3(9, 9, B), 256, 0, stream>>>(spatial_1, spatial_2, norm, nn1, nn2);
    select_topk<<<dim3(B, 2), 256, 0, stream>>>(nn1, nn2, sel_p, sel_q);
    gather_kernel<<<dim3(NLOC, 4), 256, 0, stream>>>(spatial_1, spatial_2, sel_p, sel_q, Xg);
    ata_kernel<<<dim3(12, 12, 6), 256, 0, stream>>>(Xg, pooled_1, pooled_2, M);
    colsum_kernel<<<dim3(3, 32, 6), 256, 0, stream>>>(Xg, pooled_1, pooled_2, colsum);
    std_kernel<<<dim3(3, 6), 256, 0, stream>>>(M, colsum, slots);
    cov_kernel<<<dim3(2304, 6), 256, 0, stream>>>(M, colsum, slots);
    inv_global_kernel<<<dim3(96), 256, 0, stream>>>(pooled_1, pooled_2, slots);
    inv_local_kernel<<<dim3(1200, 2), 256, 0, stream>>>(Xg, slots);
    final_kernel<<<1, 1, 0, stream>>>(slots, out);
}

// Round 2
// 786.598 us; speedup vs baseline: 1.7616x; 1.7616x over previous
//
#include <hip/hip_runtime.h>
#include <stdint.h>

typedef unsigned long long ull;
typedef unsigned int uint;
typedef unsigned short ushort;

typedef __attribute__((ext_vector_type(8))) short short8;
typedef __attribute__((ext_vector_type(4))) float floatx4;

#define B   64
#define C   768
#define HW  576
#define K   50
#define NLOC (B*K)          // 3200

// ---- workspace layout (bytes) ----
#define OFF_SLOTS   0            // 64 floats
#define OFF_COLSUM  256          // 6*768*4 = 18432
#define OFF_NN1     18688        // 64*576*8 = 294912
#define OFF_NN2     313600       // 294912
#define OFF_SELP    608512       // 2*64*50*4 = 25600
#define OFF_SELQ    634112       // 25600
#define OFF_NORM    659712       // 2*64*576*4 = 294912
#define OFF_XT      954624       // 2*64*576*768*2 = 113246208
#define OFF_XGT     114200832    // 4*768*3200*2 = 19660800
#define OFF_M       133861632    // 6*768*768*4 = 14155776
// total 148017408

#define SLOT_INVG 0
#define SLOT_STD  1   // +mat (0..5)
#define SLOT_COV  7   // +mat (0..5)
#define SLOT_INV1 13
#define SLOT_INV2 14

__device__ __forceinline__ ull umin64(ull a, ull b) { return a < b ? a : b; }

__device__ __forceinline__ float bf2f_lo(uint u) { return __uint_as_float(u << 16); }
__device__ __forceinline__ float bf2f_hi(uint u) { return __uint_as_float(u & 0xffff0000u); }
__device__ __forceinline__ float bf2f(ushort u) { return __uint_as_float(((uint)u) << 16); }

__device__ __forceinline__ ushort f2bf(float f) {
    uint u = __float_as_uint(f);
    uint r = (u + 0x7fffu + ((u >> 16) & 1u)) >> 16;   // RNE
    return (ushort)r;
}

__device__ __forceinline__ float blk_reduce_sum(float v, float* s4) {
    for (int off = 32; off > 0; off >>= 1) v += __shfl_down(v, off, 64);
    int lane = threadIdx.x & 63, w = threadIdx.x >> 6;
    if (lane == 0) s4[w] = v;
    __syncthreads();
    float r = 0.f;
    if (threadIdx.x == 0) r = s4[0] + s4[1] + s4[2] + s4[3];
    return r;
}

// ---------- convert fp32 [b][c][p] -> bf16 xT[which][b][p][c] (transpose) ----------
__global__ __launch_bounds__(256) void convert_kernel(const float* __restrict__ x1,
                                                      const float* __restrict__ x2,
                                                      ushort* __restrict__ xT) {
    int z = blockIdx.z;
    int which = z >> 6, b = z & 63;
    const float* X = which ? x2 : x1;
    int p0 = blockIdx.x * 64, c0 = blockIdx.y * 64;
    __shared__ float tile[64][65];
    const float* src = X + ((size_t)b * C + c0) * HW + p0;
    int col = threadIdx.x & 63, r0 = threadIdx.x >> 6;
    for (int rr = r0; rr < 64; rr += 4)
        tile[rr][col] = src[(size_t)rr * HW + col];
    __syncthreads();
    ushort* dst = xT + (((size_t)which * B + b) * HW + p0) * C + c0;
    int cc = (threadIdx.x & 31) * 2, pr0 = threadIdx.x >> 5;
    for (int pr = pr0; pr < 64; pr += 8) {
        ushort2 o;
        o.x = f2bf(tile[cc][pr]);
        o.y = f2bf(tile[cc + 1][pr]);
        *(ushort2*)&dst[(size_t)pr * C + cc] = o;
    }
}

// ---------- norms from bf16 xT: norm[which][b][p] = sum_c x^2 ----------
__global__ __launch_bounds__(256) void norm_kernel2(const ushort* __restrict__ xT,
                                                    float* __restrict__ norm) {
    int which = blockIdx.z, b = blockIdx.y, p0 = blockIdx.x * 64;
    int r = threadIdx.x >> 2, part = threadIdx.x & 3;
    const ushort* row = xT + (((size_t)which * B + b) * HW + p0 + r) * C + part * 192;
    float s = 0.f;
    for (int k = 0; k < 192; k += 8) {
        uint4 v = *(const uint4*)(row + k);
        float f0 = bf2f_lo(v.x), f1 = bf2f_hi(v.x);
        float f2 = bf2f_lo(v.y), f3 = bf2f_hi(v.y);
        float f4 = bf2f_lo(v.z), f5 = bf2f_hi(v.z);
        float f6 = bf2f_lo(v.w), f7 = bf2f_hi(v.w);
        s = fmaf(f0, f0, s); s = fmaf(f1, f1, s);
        s = fmaf(f2, f2, s); s = fmaf(f3, f3, s);
        s = fmaf(f4, f4, s); s = fmaf(f5, f5, s);
        s = fmaf(f6, f6, s); s = fmaf(f7, f7, s);
    }
    s += __shfl_down(s, 2, 4);
    s += __shfl_down(s, 1, 4);
    if (part == 0) norm[((size_t)which * B + b) * HW + p0 + r] = s;
}

// ---------- cdist Gram via MFMA + fused NN min reductions ----------
__global__ __launch_bounds__(256) void cdist_mfma(const ushort* __restrict__ xT,
                                                  const float* __restrict__ norm,
                                                  ull* __restrict__ nn1,
                                                  ull* __restrict__ nn2) {
    int qt = blockIdx.x, pt = blockIdx.y, b = blockIdx.z;
    const ushort* X1 = xT + ((size_t)b * HW) * C;
    const ushort* X2 = xT + (((size_t)B + b) * HW) * C;

    __shared__ char As[4096];
    __shared__ char Bs[4096];
    __shared__ ull red[64][33];

    int tid = threadIdx.x;
    int w = tid >> 6, l = tid & 63;
    int quad = l >> 4, col = l & 15;

    // staging: lane l of wave w stages LDS chunk (row sm, pos cpos); data chunk = cpos ^ swz(sm)
    int sm = w * 16 + (l >> 2);
    int cpos = l & 3;
    int cdat = cpos ^ ((sm >> 1) & 3);
    const ushort* gA = X1 + ((size_t)(pt * 64 + sm)) * C + cdat * 8;
    const ushort* gB = X2 + ((size_t)(qt * 64 + sm)) * C + cdat * 8;
    char* ldsA = As + w * 1024;
    char* ldsB = Bs + w * 1024;

    // fragment LDS byte offsets (constant over k since tile holds current window only)
    int offA[2], offB[2];
#pragma unroll
    for (int i = 0; i < 2; ++i) {
        int m_loc = 32 * (w >> 1) + 16 * i + col;
        offA[i] = m_loc * 64 + ((quad ^ ((m_loc >> 1) & 3)) * 16);
        int n_loc = 32 * (w & 1) + 16 * i + col;
        offB[i] = n_loc * 64 + ((quad ^ ((n_loc >> 1) & 3)) * 16);
    }

    floatx4 zero = {0.f, 0.f, 0.f, 0.f};
    floatx4 acc[2][2];
#pragma unroll
    for (int i = 0; i < 2; ++i)
#pragma unroll
        for (int j = 0; j < 2; ++j) acc[i][j] = zero;

    for (int k0 = 0; k0 < C; k0 += 32) {
        __syncthreads();
        __builtin_amdgcn_global_load_lds(
            (const __attribute__((address_space(1))) void*)(gA + k0),
            (__attribute__((address_space(3))) void*)ldsA, 16, 0, 0);
        __builtin_amdgcn_global_load_lds(
            (const __attribute__((address_space(1))) void*)(gB + k0),
            (__attribute__((address_space(3))) void*)ldsB, 16, 0, 0);
        __syncthreads();
        short8 a0 = *(const short8*)(As + offA[0]);
        short8 a1 = *(const short8*)(As + offA[1]);
        short8 b0 = *(const short8*)(Bs + offB[0]);
        short8 b1 = *(const short8*)(Bs + offB[1]);
        acc[0][0] = __builtin_amdgcn_mfma_f32_16x16x32_bf16(a0, b0, acc[0][0], 0, 0, 0);
        acc[0][1] = __builtin_amdgcn_mfma_f32_16x16x32_bf16(a0, b1, acc[0][1], 0, 0, 0);
        acc[1][0] = __builtin_amdgcn_mfma_f32_16x16x32_bf16(a1, b0, acc[1][0], 0, 0, 0);
        acc[1][1] = __builtin_amdgcn_mfma_f32_16x16x32_bf16(a1, b1, acc[1][1], 0, 0, 0);
    }

    const float* n1g = norm + (size_t)b * HW;
    const float* n2g = norm + ((size_t)B + b) * HW;
    float n1v[2][4], n2v[2];
#pragma unroll
    for (int i = 0; i < 2; ++i)
#pragma unroll
        for (int r = 0; r < 4; ++r)
            n1v[i][r] = n1g[pt * 64 + 32 * (w >> 1) + 16 * i + quad * 4 + r];
#pragma unroll
    for (int j = 0; j < 2; ++j)
        n2v[j] = n2g[qt * 64 + 32 * (w & 1) + 16 * j + col];

    // pass 1: per-p min over q (nn1)
#pragma unroll
    for (int i = 0; i < 2; ++i)
#pragma unroll
        for (int r = 0; r < 4; ++r) {
            int p_loc = 32 * (w >> 1) + 16 * i + quad * 4 + r;
            ull best = ~0ull;
#pragma unroll
            for (int j = 0; j < 2; ++j) {
                float d2 = fmaxf(n1v[i][r] + n2v[j] - 2.0f * acc[i][j][r], 0.0f);
                unsigned q_glob = qt * 64 + 32 * (w & 1) + 16 * j + col;
                best = umin64(best, ((ull)__float_as_uint(d2) << 32) | q_glob);
            }
            red[p_loc][(w & 1) * 16 + col] = best;
        }
    __syncthreads();
    if (tid < 64) {
        ull m = ~0ull;
#pragma unroll
        for (int x = 0; x < 32; ++x) m = umin64(m, red[tid][x]);
        atomicMin(&nn1[(size_t)b * HW + pt * 64 + tid], m);
    }
    __syncthreads();
    // pass 2: per-q min over p (nn2)
#pragma unroll
    for (int j = 0; j < 2; ++j) {
        int q_loc = 32 * (w & 1) + 16 * j + col;
        ull best = ~0ull;
#pragma unroll
        for (int i = 0; i < 2; ++i)
#pragma unroll
            for (int r = 0; r < 4; ++r) {
                float d2 = fmaxf(n1v[i][r] + n2v[j] - 2.0f * acc[i][j][r], 0.0f);
                unsigned p_glob = pt * 64 + 32 * (w >> 1) + 16 * i + quad * 4 + r;
                best = umin64(best, ((ull)__float_as_uint(d2) << 32) | p_glob);
            }
        red[q_loc][(w >> 1) * 4 + quad] = best;
    }
    __syncthreads();
    if (tid < 64) {
        ull m = ~0ull;
#pragma unroll
        for (int x = 0; x < 8; ++x) m = umin64(m, red[tid][x]);
        atomicMin(&nn2[(size_t)b * HW + qt * 64 + tid], m);
    }
}

// ---------------- top-k (k=50 smallest) per (batch, direction) ----------------
__global__ __launch_bounds__(256) void select_topk(const ull* __restrict__ nn1,
                                                   const ull* __restrict__ nn2,
                                                   int* __restrict__ sel_p,
                                                   int* __restrict__ sel_q) {
    int b = blockIdx.x, dir = blockIdx.y;
    const ull* nn = dir ? nn2 : nn1;
    __shared__ ull skey[HW];
    __shared__ unsigned sq[HW];
    __shared__ ull red[256];
    int tid = threadIdx.x;
    for (int p = tid; p < HW; p += 256) {
        ull k = nn[(size_t)b * HW + p];
        skey[p] = (k & 0xFFFFFFFF00000000ull) | (unsigned)p;
        sq[p] = (unsigned)(k & 0xFFFFFFFFu);
    }
    __syncthreads();
    for (int it = 0; it < K; ++it) {
        ull m = ~0ull;
        for (int p = tid; p < HW; p += 256) m = umin64(m, skey[p]);
        red[tid] = m;
        __syncthreads();
        for (int s = 128; s > 0; s >>= 1) {
            if (tid < s) red[tid] = umin64(red[tid], red[tid + s]);
            __syncthreads();
        }
        if (tid == 0) {
            unsigned pstar = (unsigned)(red[0] & 0xFFFFFFFFu);
            sel_p[(dir * B + b) * K + it] = (int)pstar;
            sel_q[(dir * B + b) * K + it] = (int)sq[pstar];
            skey[pstar] = ~0ull;
        }
        __syncthreads();
    }
}

// ---------- gather into XgT[s][c][i] (bf16, channel-major) ----------
// s: 0=x1[sel_p d0] 1=x2[sel_q d0] 2=x2[sel_p d1] 3=x1[sel_q d1]
__global__ __launch_bounds__(256) void gather_t(const ushort* __restrict__ xT,
                                                const int* __restrict__ sel_p,
                                                const int* __restrict__ sel_q,
                                                ushort* __restrict__ XgT) {
    int b = blockIdx.x, s = blockIdx.y;
    int dir = s >> 1;
    int whichsrc = (s == 1 || s == 2) ? 1 : 0;
    const int* sel = ((s & 1) ? sel_q : sel_p) + (dir * B + b) * K;
    __shared__ int idx[K];
    if (threadIdx.x < K) idx[threadIdx.x] = sel[threadIdx.x];
    __syncthreads();
    int j = threadIdx.x & 63;
    int c0 = threadIdx.x >> 6;
    if (j >= K) return;
    const ushort* row = xT + (((size_t)whichsrc * B + b) * HW + idx[j]) * C;
    ushort* out = XgT + (size_t)s * C * NLOC + b * K + j;
    for (int c = c0; c < C; c += 4)
        out[(size_t)c * NLOC] = row[c];
}

// ---------- M = X^T X via MFMA for mats 0..3 (X = XgT[mat], [C][NLOC]) ----------
__global__ __launch_bounds__(256) void ata_mfma(const ushort* __restrict__ XgT,
                                                float* __restrict__ M) {
    int ct = blockIdx.x, rt = blockIdx.y, mat = blockIdx.z;
    const ushort* X = XgT + (size_t)mat * C * NLOC;
    __shared__ char As[4096];
    __shared__ char Bs[4096];
    int tid = threadIdx.x;
    int w = tid >> 6, l = tid & 63;
    int quad = l >> 4, col = l & 15;

    int sm = w * 16 + (l >> 2);
    int cpos = l & 3;
    int cdat = cpos ^ ((sm >> 1) & 3);
    const ushort* gA = X + ((size_t)(rt * 64 + sm)) * NLOC + cdat * 8;
    const ushort* gB = X + ((size_t)(ct * 64 + sm)) * NLOC + cdat * 8;
    char* ldsA = As + w * 1024;
    char* ldsB = Bs + w * 1024;

    int offA[2], offB[2];
#pragma unroll
    for (int i = 0; i < 2; ++i) {
        int m_loc = 32 * (w >> 1) + 16 * i + col;
        offA[i] = m_loc * 64 + ((quad ^ ((m_loc >> 1) & 3)) * 16);
        int n_loc = 32 * (w & 1) + 16 * i + col;
        offB[i] = n_loc * 64 + ((quad ^ ((n_loc >> 1) & 3)) * 16);
    }

    floatx4 zero = {0.f, 0.f, 0.f, 0.f};
    floatx4 acc[2][2];
#pragma unroll
    for (int i = 0; i < 2; ++i)
#pragma unroll
        for (int j = 0; j < 2; ++j) acc[i][j] = zero;

    for (int k0 = 0; k0 < NLOC; k0 += 32) {
        __syncthreads();
        __builtin_amdgcn_global_load_lds(
            (const __attribute__((address_space(1))) void*)(gA + k0),
            (__attribute__((address_space(3))) void*)ldsA, 16, 0, 0);
        __builtin_amdgcn_global_load_lds(
            (const __attribute__((address_space(1))) void*)(gB + k0),
            (__attribute__((address_space(3))) void*)ldsB, 16, 0, 0);
        __syncthreads();
        short8 a0 = *(const short8*)(As + offA[0]);
        short8 a1 = *(const short8*)(As + offA[1]);
        short8 b0 = *(const short8*)(Bs + offB[0]);
        short8 b1 = *(const short8*)(Bs + offB[1]);
        acc[0][0] = __builtin_amdgcn_mfma_f32_16x16x32_bf16(a0, b0, acc[0][0], 0, 0, 0);
        acc[0][1] = __builtin_amdgcn_mfma_f32_16x16x32_bf16(a0, b1, acc[0][1], 0, 0, 0);
        acc[1][0] = __builtin_amdgcn_mfma_f32_16x16x32_bf16(a1, b0, acc[1][0], 0, 0, 0);
        acc[1][1] = __builtin_amdgcn_mfma_f32_16x16x32_bf16(a1, b1, acc[1][1], 0, 0, 0);
    }

    float* Mo = M + (size_t)mat * C * C;
#pragma unroll
    for (int i = 0; i < 2; ++i)
#pragma unroll
        for (int j = 0; j < 2; ++j)
#pragma unroll
            for (int r = 0; r < 4; ++r) {
                int row = rt * 64 + 32 * (w >> 1) + 16 * i + quad * 4 + r;
                int cc = ct * 64 + 32 * (w & 1) + 16 * j + col;
                Mo[(size_t)row * C + cc] = acc[i][j][r];
            }
}

// ---------- fp32 X^T X for pooled mats (4,5), n=64 ----------
__global__ __launch_bounds__(256) void ata_pooled(const float* __restrict__ p1,
                                                  const float* __restrict__ p2,
                                                  float* __restrict__ M) {
    int mat = 4 + blockIdx.z;
    const float* X = (mat == 4) ? p1 : p2;
    int n = B;
    float* Mo = M + (size_t)mat * C * C;
    int ct = blockIdx.x, rt = blockIdx.y;

    __shared__ float As[16][64];
    __shared__ float Bs[16][64];
    int tid = threadIdx.x;
    int tx = tid & 15, ty = tid >> 4;
    int lr = tid >> 4, lc = (tid & 15) * 4;

    float acc[4][4] = {};
    for (int k0 = 0; k0 < n; k0 += 16) {
        float4 av = *(const float4*)&X[(size_t)(k0 + lr) * C + rt * 64 + lc];
        float4 bv = *(const float4*)&X[(size_t)(k0 + lr) * C + ct * 64 + lc];
        __syncthreads();
        *(float4*)&As[lr][lc] = av;
        *(float4*)&Bs[lr][lc] = bv;
        __syncthreads();
#pragma unroll
        for (int kk = 0; kk < 16; ++kk) {
            float4 af = *(const float4*)&As[kk][ty * 4];
            float4 bf = *(const float4*)&Bs[kk][tx * 4];
            float a[4] = {af.x, af.y, af.z, af.w};
            float bb[4] = {bf.x, bf.y, bf.z, bf.w};
#pragma unroll
            for (int i = 0; i < 4; ++i)
#pragma unroll
                for (int j = 0; j < 4; ++j)
                    acc[i][j] = fmaf(a[i], bb[j], acc[i][j]);
        }
    }
#pragma unroll
    for (int i = 0; i < 4; ++i) {
        float4 o = {acc[i][0], acc[i][1], acc[i][2], acc[i][3]};
        *(float4*)&Mo[(size_t)(rt * 64 + ty * 4 + i) * C + ct * 64 + tx * 4] = o;
    }
}

// ---------- colsum for mats 0..3 from XgT ----------
__global__ __launch_bounds__(256) void colsum4_kernel(const ushort* __restrict__ XgT,
                                                      float* __restrict__ colsum) {
    int mat = blockIdx.y, cb = blockIdx.x * 4;
    int r = threadIdx.x >> 6, lane = threadIdx.x & 63;
    const ushort* row = XgT + ((size_t)mat * C + cb + r) * NLOC;
    float s = 0.f;
    for (int i = lane; i < NLOC; i += 64) s += bf2f(row[i]);
    for (int off = 32; off > 0; off >>= 1) s += __shfl_down(s, off, 64);
    if (lane == 0) colsum[mat * C + cb + r] = s;
}

// ---------- colsum for pooled mats (4,5) ----------
__global__ __launch_bounds__(256) void colsum_pooled(const float* __restrict__ p1,
                                                     const float* __restrict__ p2,
                                                     float* __restrict__ colsum) {
    int mat = 4 + blockIdx.z;
    const float* X = (mat == 4) ? p1 : p2;
    int n = B;
    int c = blockIdx.x * 256 + threadIdx.x;
    if (c >= C) return;
    int chunk = (n + 31) / 32;
    int r0 = blockIdx.y * chunk;
    int r1 = min(n, r0 + chunk);
    float s = 0.f;
    for (int r = r0; r < r1; ++r) s += X[(size_t)r * C + c];
    atomicAdd(&colsum[mat * C + c], s);
}

// ---------- std term ----------
__global__ __launch_bounds__(256) void std_kernel(const float* __restrict__ M,
                                                  const float* __restrict__ colsum,
                                                  float* __restrict__ slots) {
    int mat = blockIdx.y;
    float n = (mat < 4) ? (float)NLOC : (float)B;
    int c = blockIdx.x * 256 + threadIdx.x;
    float r = 0.f;
    if (c < C) {
        float mcc = M[(size_t)mat * C * C + (size_t)c * C + c];
        float cs = colsum[mat * C + c];
        float var = (mcc - cs * cs / n) / (n - 1.0f);
        float sd = sqrtf(var + 1e-5f);
        float g = 1.0f - sd;
        r = g > 0.f ? g : 0.f;
    }
    __shared__ float s4[4];
    float t = blk_reduce_sum(r, s4);
    if (threadIdx.x == 0) atomicAdd(&slots[SLOT_STD + mat], t);
}

// ---------- cov term ----------
__global__ __launch_bounds__(256) void cov_kernel(const float* __restrict__ M,
                                                  const float* __restrict__ colsum,
                                                  float* __restrict__ slots) {
    int mat = blockIdx.y;
    float n = (mat < 4) ? (float)NLOC : (float)B;
    int idx = blockIdx.x * 256 + threadIdx.x;
    float r = 0.f;
    if (idx < C * C) {
        int i = idx / C, j = idx % C;
        if (i != j) {
            float m = M[(size_t)mat * C * C + idx];
            float cv = (m - colsum[mat * C + i] * colsum[mat * C + j] / n) / (n - 1.0f);
            r = cv * cv;
        }
    }
    __shared__ float s4[4];
    float t = blk_reduce_sum(r, s4);
    if (threadIdx.x == 0) atomicAdd(&slots[SLOT_COV + mat], t);
}

// ---------- invariance terms ----------
__global__ __launch_bounds__(256) void inv_global_kernel(const float* __restrict__ p1,
                                                         const float* __restrict__ p2,
                                                         float* __restrict__ slots) {
    int idx = blockIdx.x * 256 + threadIdx.x;
    int stride = gridDim.x * 256;
    float s = 0.f;
    for (int i = idx; i < B * C; i += stride) {
        float d = p1[i] - p2[i];
        s = fmaf(d, d, s);
    }
    __shared__ float s4[4];
    float t = blk_reduce_sum(s, s4);
    if (threadIdx.x == 0) atomicAdd(&slots[SLOT_INVG], t);
}

__global__ __launch_bounds__(256) void inv_local2(const ushort* __restrict__ XgT,
                                                  float* __restrict__ slots) {
    int pair = blockIdx.y;
    const uint* A4 = (const uint*)(XgT + (size_t)(2 * pair) * C * NLOC);
    const uint* B4 = (const uint*)(XgT + (size_t)(2 * pair + 1) * C * NLOC);
    int idx = blockIdx.x * 256 + threadIdx.x;
    int stride = gridDim.x * 256;
    int n = C * NLOC / 2;
    float s = 0.f;
    for (int i = idx; i < n; i += stride) {
        uint ua = A4[i], ub = B4[i];
        float d0 = bf2f_lo(ua) - bf2f_lo(ub);
        float d1 = bf2f_hi(ua) - bf2f_hi(ub);
        s = fmaf(d0, d0, s);
        s = fmaf(d1, d1, s);
    }
    __shared__ float s4[4];
    float t = blk_reduce_sum(s, s4);
    if (threadIdx.x == 0) atomicAdd(&slots[(pair == 0) ? SLOT_INV1 : SLOT_INV2], t);
}

// ---------- final combine ----------
__global__ void final_kernel(const float* __restrict__ slots, float* __restrict__ out) {
    float std_t[6], cov_t[6];
    for (int m = 0; m < 6; ++m) {
        std_t[m] = slots[SLOT_STD + m] / (float)C * 0.5f;
        cov_t[m] = slots[SLOT_COV + m] / (float)C;
    }
    float inv_g = slots[SLOT_INVG] / (float)(B * C);
    float global_loss = 25.0f * inv_g + 25.0f * (std_t[4] + std_t[5]) + (cov_t[4] + cov_t[5]);
    float inv1 = 25.0f * slots[SLOT_INV1] / (float)(NLOC * C);
    float inv2 = 25.0f * slots[SLOT_INV2] / (float)(NLOC * C);
    float var1 = 25.0f * (std_t[0] + std_t[1]);
    float var2 = 25.0f * (std_t[2] + std_t[3]);
    float cov1 = cov_t[0] + cov_t[1];
    float cov2 = cov_t[2] + cov_t[3];
    float local_loss = (inv1 + inv2) * 0.5f + (var1 + var2) * 0.5f + (cov1 + cov2) * 0.5f;
    out[0] = 0.5f * global_loss + 0.5f * local_loss;
}

extern "C" void kernel_launch(void* const* d_in, const int* in_sizes, int n_in,
                              void* d_out, int out_size, void* d_ws, size_t ws_size,
                              hipStream_t stream) {
    const float* spatial_1 = (const float*)d_in[0];
    const float* pooled_1  = (const float*)d_in[1];
    const float* spatial_2 = (const float*)d_in[2];
    const float* pooled_2  = (const float*)d_in[3];
    float* out = (float*)d_out;

    char* ws = (char*)d_ws;
    float*  slots  = (float*)(ws + OFF_SLOTS);
    float*  colsum = (float*)(ws + OFF_COLSUM);
    ull*    nn1    = (ull*)(ws + OFF_NN1);
    ull*    nn2    = (ull*)(ws + OFF_NN2);
    int*    sel_p  = (int*)(ws + OFF_SELP);
    int*    sel_q  = (int*)(ws + OFF_SELQ);
    float*  norm   = (float*)(ws + OFF_NORM);
    ushort* xT     = (ushort*)(ws + OFF_XT);
    ushort* XgT    = (ushort*)(ws + OFF_XGT);
    float*  M      = (float*)(ws + OFF_M);

    hipMemsetAsync(ws, 0, OFF_NN1, stream);                       // slots + colsum
    hipMemsetAsync(ws + OFF_NN1, 0xFF, OFF_SELP - OFF_NN1, stream); // nn keys

    convert_kernel<<<dim3(9, 12, 128), 256, 0, stream>>>(spatial_1, spatial_2, xT);
    norm_kernel2<<<dim3(9, B, 2), 256, 0, stream>>>(xT, norm);
    cdist_mfma<<<dim3(9, 9, B), 256, 0, stream>>>(xT, norm, nn1, nn2);
    select_topk<<<dim3(B, 2), 256, 0, stream>>>(nn1, nn2, sel_p, sel_q);
    gather_t<<<dim3(B, 4), 256, 0, stream>>>(xT, sel_p, sel_q, XgT);
    ata_mfma<<<dim3(12, 12, 4), 256, 0, stream>>>(XgT, M);
    ata_pooled<<<dim3(12, 12, 2), 256, 0, stream>>>(pooled_1, pooled_2, M);
    colsum4_kernel<<<dim3(192, 4), 256, 0, stream>>>(XgT, colsum);
    colsum_pooled<<<dim3(3, 32, 2), 256, 0, stream>>>(pooled_1, pooled_2, colsum);
    std_kernel<<<dim3(3, 6), 256, 0, stream>>>(M, colsum, slots);
    cov_kernel<<<dim3(2304, 6), 256, 0, stream>>>(M, colsum, slots);
    inv_global_kernel<<<dim3(96), 256, 0, stream>>>(pooled_1, pooled_2, slots);
    inv_local2<<<dim3(1200, 2), 256, 0, stream>>>(XgT, slots);
    final_kernel<<<1, 1, 0, stream>>>(slots, out);
}

// Round 3
// 552.461 us; speedup vs baseline: 2.5082x; 1.4238x over previous
//
#include <hip/hip_runtime.h>
#include <stdint.h>

typedef unsigned long long ull;
typedef unsigned int uint;
typedef unsigned short ushort;

typedef __attribute__((ext_vector_type(8))) short short8;
typedef __attribute__((ext_vector_type(4))) float floatx4;

#define B   64
#define C   768
#define HW  576
#define K   50
#define NLOC (B*K)          // 3200

// ---- workspace layout (bytes) ----
#define OFF_SLOTS   0            // 64 floats
#define OFF_COLSUM  256          // 6*768*4 = 18432
#define OFF_NN1     18688        // 64*576*8 = 294912
#define OFF_NN2     313600       // 294912
#define OFF_SELP    608512       // 2*64*50*4 = 25600
#define OFF_SELQ    634112       // 25600
#define OFF_NORM    659712       // 2*64*576*4 = 294912
#define OFF_XT      954624       // 2*64*576*768*2 = 113246208  (dead after gather -> reused as Mp)
#define OFF_MP      OFF_XT       // 4 mats * 2 splits * 768*768*4 = 18874368 (fits in XT region)
#define OFF_XGT     114200832    // 4*768*3200*2 = 19660800
#define OFF_M       133861632    // 6*768*768*4 = 14155776
// total 148017408

#define SLOT_INVG 0
#define SLOT_STD  1   // +mat (0..5)
#define SLOT_COV  7   // +mat (0..5)
#define SLOT_INV1 13
#define SLOT_INV2 14

__device__ __forceinline__ ull umin64(ull a, ull b) { return a < b ? a : b; }

__device__ __forceinline__ float bf2f_lo(uint u) { return __uint_as_float(u << 16); }
__device__ __forceinline__ float bf2f_hi(uint u) { return __uint_as_float(u & 0xffff0000u); }
__device__ __forceinline__ float bf2f(ushort u) { return __uint_as_float(((uint)u) << 16); }

__device__ __forceinline__ ushort f2bf(float f) {
    uint u = __float_as_uint(f);
    uint r = (u + 0x7fffu + ((u >> 16) & 1u)) >> 16;   // RNE
    return (ushort)r;
}

__device__ __forceinline__ float blk_reduce_sum(float v, float* s4) {
    for (int off = 32; off > 0; off >>= 1) v += __shfl_down(v, off, 64);
    int lane = threadIdx.x & 63, w = threadIdx.x >> 6;
    if (lane == 0) s4[w] = v;
    __syncthreads();
    float r = 0.f;
    if (threadIdx.x == 0) r = s4[0] + s4[1] + s4[2] + s4[3];
    return r;
}

// ---------- convert fp32 [b][c][p] -> bf16 xT[which][b][p][c] (transpose) ----------
__global__ __launch_bounds__(256) void convert_kernel(const float* __restrict__ x1,
                                                      const float* __restrict__ x2,
                                                      ushort* __restrict__ xT) {
    int z = blockIdx.z;
    int which = z >> 6, b = z & 63;
    const float* X = which ? x2 : x1;
    int p0 = blockIdx.x * 64, c0 = blockIdx.y * 64;
    __shared__ float tile[64][65];
    const float* src = X + ((size_t)b * C + c0) * HW + p0;
    int col = threadIdx.x & 63, r0 = threadIdx.x >> 6;
    for (int rr = r0; rr < 64; rr += 4)
        tile[rr][col] = src[(size_t)rr * HW + col];
    __syncthreads();
    ushort* dst = xT + (((size_t)which * B + b) * HW + p0) * C + c0;
    int cc = (threadIdx.x & 31) * 2, pr0 = threadIdx.x >> 5;
    for (int pr = pr0; pr < 64; pr += 8) {
        ushort2 o;
        o.x = f2bf(tile[cc][pr]);
        o.y = f2bf(tile[cc + 1][pr]);
        *(ushort2*)&dst[(size_t)pr * C + cc] = o;
    }
}

// ---------- norms from bf16 xT ----------
__global__ __launch_bounds__(256) void norm_kernel2(const ushort* __restrict__ xT,
                                                    float* __restrict__ norm) {
    int which = blockIdx.z, b = blockIdx.y, p0 = blockIdx.x * 64;
    int r = threadIdx.x >> 2, part = threadIdx.x & 3;
    const ushort* row = xT + (((size_t)which * B + b) * HW + p0 + r) * C + part * 192;
    float s = 0.f;
    for (int k = 0; k < 192; k += 8) {
        uint4 v = *(const uint4*)(row + k);
        float f0 = bf2f_lo(v.x), f1 = bf2f_hi(v.x);
        float f2 = bf2f_lo(v.y), f3 = bf2f_hi(v.y);
        float f4 = bf2f_lo(v.z), f5 = bf2f_hi(v.z);
        float f6 = bf2f_lo(v.w), f7 = bf2f_hi(v.w);
        s = fmaf(f0, f0, s); s = fmaf(f1, f1, s);
        s = fmaf(f2, f2, s); s = fmaf(f3, f3, s);
        s = fmaf(f4, f4, s); s = fmaf(f5, f5, s);
        s = fmaf(f6, f6, s); s = fmaf(f7, f7, s);
    }
    s += __shfl_down(s, 2, 4);
    s += __shfl_down(s, 1, 4);
    if (part == 0) norm[((size_t)which * B + b) * HW + p0 + r] = s;
}

// ---------- cdist Gram via MFMA, 128x64 tile, BK=64 (two BK=32 subtiles) ----------
__global__ __launch_bounds__(256) void cdist_mfma(const ushort* __restrict__ xT,
                                                  const float* __restrict__ norm,
                                                  ull* __restrict__ nn1,
                                                  ull* __restrict__ nn2) {
    int qt = blockIdx.x, pt = blockIdx.y, b = blockIdx.z;
    const ushort* X1 = xT + ((size_t)b * HW) * C;
    const ushort* X2 = xT + (((size_t)B + b) * HW) * C;

    __shared__ long long pool_ll[3072];           // 24576 B: A(16384) + B(8192); red overlays
    char* As = (char*)pool_ll;
    char* Bs = As + 16384;

    int tid = threadIdx.x;
    int w = tid >> 6, l = tid & 63;
    int quad = l >> 4, col = l & 15;

    // ---- staging descriptors ----
    int smA = tid >> 2;                 // 0..63 (row within 64-row block)
    int posA = tid & 3;
    const ushort* gA[2][2];             // [subtile s][rowblock rb]
    char* ldsA[2][2];
    const ushort* gB[2];
    char* ldsB[2];
#pragma unroll
    for (int rb = 0; rb < 2; ++rb) {
        int sm = rb * 64 + smA;         // LDS row 0..127
        int cdat = posA ^ ((sm >> 1) & 3);
        int p = pt * 128 + sm;
        int pr = p < HW ? p : (HW - 1); // clamp; masked later
#pragma unroll
        for (int s = 0; s < 2; ++s) {
            gA[s][rb] = X1 + (size_t)pr * C + s * 32 + cdat * 8;
            ldsA[s][rb] = As + s * 8192 + rb * 4096 + w * 1024;
        }
    }
    {
        int sm = smA;
        int cdat = posA ^ ((sm >> 1) & 3);
        int q = qt * 64 + sm;
#pragma unroll
        for (int s = 0; s < 2; ++s) {
            gB[s] = X2 + (size_t)q * C + s * 32 + cdat * 8;
            ldsB[s] = Bs + s * 4096 + w * 1024;
        }
    }

    // ---- fragment LDS offsets ----
    int offA[2], offB[4];
#pragma unroll
    for (int i = 0; i < 2; ++i) {
        int m_loc = w * 32 + i * 16 + col;           // 0..127
        offA[i] = m_loc * 64 + ((quad ^ ((m_loc >> 1) & 3)) * 16);
    }
#pragma unroll
    for (int j = 0; j < 4; ++j) {
        int n_loc = j * 16 + col;                    // 0..63
        offB[j] = n_loc * 64 + ((quad ^ ((n_loc >> 1) & 3)) * 16);
    }

    floatx4 zero = {0.f, 0.f, 0.f, 0.f};
    floatx4 acc[2][4];
#pragma unroll
    for (int i = 0; i < 2; ++i)
#pragma unroll
        for (int j = 0; j < 4; ++j) acc[i][j] = zero;

    for (int k0 = 0; k0 < C; k0 += 64) {
        __syncthreads();
#pragma unroll
        for (int s = 0; s < 2; ++s) {
#pragma unroll
            for (int rb = 0; rb < 2; ++rb)
                __builtin_amdgcn_global_load_lds(
                    (const __attribute__((address_space(1))) void*)(gA[s][rb] + k0),
                    (__attribute__((address_space(3))) void*)ldsA[s][rb], 16, 0, 0);
            __builtin_amdgcn_global_load_lds(
                (const __attribute__((address_space(1))) void*)(gB[s] + k0),
                (__attribute__((address_space(3))) void*)ldsB[s], 16, 0, 0);
        }
        __syncthreads();
#pragma unroll
        for (int s = 0; s < 2; ++s) {
            short8 a0 = *(const short8*)(As + s * 8192 + offA[0]);
            short8 a1 = *(const short8*)(As + s * 8192 + offA[1]);
            short8 b0 = *(const short8*)(Bs + s * 4096 + offB[0]);
            short8 b1 = *(const short8*)(Bs + s * 4096 + offB[1]);
            short8 b2 = *(const short8*)(Bs + s * 4096 + offB[2]);
            short8 b3 = *(const short8*)(Bs + s * 4096 + offB[3]);
            acc[0][0] = __builtin_amdgcn_mfma_f32_16x16x32_bf16(a0, b0, acc[0][0], 0, 0, 0);
            acc[0][1] = __builtin_amdgcn_mfma_f32_16x16x32_bf16(a0, b1, acc[0][1], 0, 0, 0);
            acc[0][2] = __builtin_amdgcn_mfma_f32_16x16x32_bf16(a0, b2, acc[0][2], 0, 0, 0);
            acc[0][3] = __builtin_amdgcn_mfma_f32_16x16x32_bf16(a0, b3, acc[0][3], 0, 0, 0);
            acc[1][0] = __builtin_amdgcn_mfma_f32_16x16x32_bf16(a1, b0, acc[1][0], 0, 0, 0);
            acc[1][1] = __builtin_amdgcn_mfma_f32_16x16x32_bf16(a1, b1, acc[1][1], 0, 0, 0);
            acc[1][2] = __builtin_amdgcn_mfma_f32_16x16x32_bf16(a1, b2, acc[1][2], 0, 0, 0);
            acc[1][3] = __builtin_amdgcn_mfma_f32_16x16x32_bf16(a1, b3, acc[1][3], 0, 0, 0);
        }
    }
    __syncthreads();   // before overlaying red on the tile buffers

    typedef ull row17[17];
    row17* red = (row17*)pool_ll;     // [128][17] = 17408 B <= 24576

    const float* n1g = norm + (size_t)b * HW;
    const float* n2g = norm + ((size_t)B + b) * HW;
    float n1v[2][4], n2v[4];
    bool  valid[2][4];
#pragma unroll
    for (int i = 0; i < 2; ++i)
#pragma unroll
        for (int r = 0; r < 4; ++r) {
            int p = pt * 128 + w * 32 + i * 16 + quad * 4 + r;
            valid[i][r] = (p < HW);
            n1v[i][r] = n1g[p < HW ? p : (HW - 1)];
        }
#pragma unroll
    for (int j = 0; j < 4; ++j)
        n2v[j] = n2g[qt * 64 + j * 16 + col];

    // pass 1: per-p min over q
#pragma unroll
    for (int i = 0; i < 2; ++i)
#pragma unroll
        for (int r = 0; r < 4; ++r) {
            int p_loc = w * 32 + i * 16 + quad * 4 + r;
            ull best = ~0ull;
#pragma unroll
            for (int j = 0; j < 4; ++j) {
                float d2 = fmaxf(n1v[i][r] + n2v[j] - 2.0f * acc[i][j][r], 0.0f);
                unsigned q_glob = qt * 64 + j * 16 + col;
                best = umin64(best, ((ull)__float_as_uint(d2) << 32) | q_glob);
            }
            red[p_loc][col] = best;
        }
    __syncthreads();
    if (tid < 128) {
        int p_glob = pt * 128 + tid;
        ull m = ~0ull;
#pragma unroll
        for (int x = 0; x < 16; ++x) m = umin64(m, red[tid][x]);
        if (p_glob < HW) atomicMin(&nn1[(size_t)b * HW + p_glob], m);
    }
    __syncthreads();
    // pass 2: per-q min over p (masked for invalid p)
#pragma unroll
    for (int j = 0; j < 4; ++j) {
        int q_loc = j * 16 + col;
        ull best = ~0ull;
#pragma unroll
        for (int i = 0; i < 2; ++i)
#pragma unroll
            for (int r = 0; r < 4; ++r) {
                if (!valid[i][r]) continue;
                float d2 = fmaxf(n1v[i][r] + n2v[j] - 2.0f * acc[i][j][r], 0.0f);
                unsigned p_glob = pt * 128 + w * 32 + i * 16 + quad * 4 + r;
                best = umin64(best, ((ull)__float_as_uint(d2) << 32) | p_glob);
            }
        red[q_loc][w * 4 + quad] = best;
    }
    __syncthreads();
    if (tid < 64) {
        ull m = ~0ull;
#pragma unroll
        for (int x = 0; x < 16; ++x) m = umin64(m, red[tid][x]);
        atomicMin(&nn2[(size_t)b * HW + qt * 64 + tid], m);
    }
}

// ---------- top-k: one wave per (b,dir), keys in registers ----------
__global__ __launch_bounds__(64) void select_topk_wave(const ull* __restrict__ nn1,
                                                       const ull* __restrict__ nn2,
                                                       int* __restrict__ sel_p,
                                                       int* __restrict__ sel_q) {
    int b = blockIdx.x, dir = blockIdx.y;
    const ull* nn = dir ? nn2 : nn1;
    int lane = threadIdx.x;
    ull key[9]; uint qv[9];
#pragma unroll
    for (int r = 0; r < 9; ++r) {
        int p = r * 64 + lane;
        ull e = nn[(size_t)b * HW + p];
        key[r] = (e & 0xFFFFFFFF00000000ull) | (unsigned)p;
        qv[r] = (uint)(e & 0xFFFFFFFFu);
    }
    int* sp = sel_p + (dir * B + b) * K;
    int* sq = sel_q + (dir * B + b) * K;
    for (int it = 0; it < K; ++it) {
        ull m = key[0];
#pragma unroll
        for (int r = 1; r < 9; ++r) m = umin64(m, key[r]);
#pragma unroll
        for (int off = 32; off > 0; off >>= 1) m = umin64(m, __shfl_xor(m, off, 64));
#pragma unroll
        for (int r = 0; r < 9; ++r) {
            if (key[r] == m) {
                sp[it] = (int)(uint)(m & 0xFFFFFFFFu);
                sq[it] = (int)qv[r];
                key[r] = ~0ull;
            }
        }
    }
}

// ---------- gather into XgT[s][c][i] ----------
__global__ __launch_bounds__(256) void gather_t(const ushort* __restrict__ xT,
                                                const int* __restrict__ sel_p,
                                                const int* __restrict__ sel_q,
                                                ushort* __restrict__ XgT) {
    int b = blockIdx.x, s = blockIdx.y;
    int dir = s >> 1;
    int whichsrc = (s == 1 || s == 2) ? 1 : 0;
    const int* sel = ((s & 1) ? sel_q : sel_p) + (dir * B + b) * K;
    __shared__ int idx[K];
    if (threadIdx.x < K) idx[threadIdx.x] = sel[threadIdx.x];
    __syncthreads();
    int j = threadIdx.x & 63;
    int c0 = threadIdx.x >> 6;
    if (j >= K) return;
    const ushort* row = xT + (((size_t)whichsrc * B + b) * HW + idx[j]) * C;
    ushort* out = XgT + (size_t)s * C * NLOC + b * K + j;
    for (int c = c0; c < C; c += 4)
        out[(size_t)c * NLOC] = row[c];
}

// ---------- Mp[mat][split] = partial X^T X via MFMA, BK=64, split-K=2 ----------
__global__ __launch_bounds__(256) void ata_mfma(const ushort* __restrict__ XgT,
                                                float* __restrict__ Mp) {
    int ct = blockIdx.x, rt = blockIdx.y;
    int mat = blockIdx.z >> 1, split = blockIdx.z & 1;
    const ushort* X = XgT + (size_t)mat * C * NLOC;
    __shared__ char As[8192];
    __shared__ char Bs[8192];
    int tid = threadIdx.x;
    int w = tid >> 6, l = tid & 63;
    int quad = l >> 4, col = l & 15;

    int sm = tid >> 2, pos = tid & 3;
    int cdat = pos ^ ((sm >> 1) & 3);
    const ushort* gA[2]; char* ldsA[2];
    const ushort* gB[2]; char* ldsB[2];
#pragma unroll
    for (int s = 0; s < 2; ++s) {
        gA[s] = X + (size_t)(rt * 64 + sm) * NLOC + split * 1600 + s * 32 + cdat * 8;
        gB[s] = X + (size_t)(ct * 64 + sm) * NLOC + split * 1600 + s * 32 + cdat * 8;
        ldsA[s] = As + s * 4096 + w * 1024;
        ldsB[s] = Bs + s * 4096 + w * 1024;
    }

    int offA[2], offB[2];
#pragma unroll
    for (int i = 0; i < 2; ++i) {
        int m_loc = 32 * (w >> 1) + 16 * i + col;
        offA[i] = m_loc * 64 + ((quad ^ ((m_loc >> 1) & 3)) * 16);
        int n_loc = 32 * (w & 1) + 16 * i + col;
        offB[i] = n_loc * 64 + ((quad ^ ((n_loc >> 1) & 3)) * 16);
    }

    floatx4 zero = {0.f, 0.f, 0.f, 0.f};
    floatx4 acc[2][2];
#pragma unroll
    for (int i = 0; i < 2; ++i)
#pragma unroll
        for (int j = 0; j < 2; ++j) acc[i][j] = zero;

    for (int k0 = 0; k0 < 1600; k0 += 64) {
        __syncthreads();
#pragma unroll
        for (int s = 0; s < 2; ++s) {
            __builtin_amdgcn_global_load_lds(
                (const __attribute__((address_space(1))) void*)(gA[s] + k0),
                (__attribute__((address_space(3))) void*)ldsA[s], 16, 0, 0);
            __builtin_amdgcn_global_load_lds(
                (const __attribute__((address_space(1))) void*)(gB[s] + k0),
                (__attribute__((address_space(3))) void*)ldsB[s], 16, 0, 0);
        }
        __syncthreads();
#pragma unroll
        for (int s = 0; s < 2; ++s) {
            short8 a0 = *(const short8*)(As + s * 4096 + offA[0]);
            short8 a1 = *(const short8*)(As + s * 4096 + offA[1]);
            short8 b0 = *(const short8*)(Bs + s * 4096 + offB[0]);
            short8 b1 = *(const short8*)(Bs + s * 4096 + offB[1]);
            acc[0][0] = __builtin_amdgcn_mfma_f32_16x16x32_bf16(a0, b0, acc[0][0], 0, 0, 0);
            acc[0][1] = __builtin_amdgcn_mfma_f32_16x16x32_bf16(a0, b1, acc[0][1], 0, 0, 0);
            acc[1][0] = __builtin_amdgcn_mfma_f32_16x16x32_bf16(a1, b0, acc[1][0], 0, 0, 0);
            acc[1][1] = __builtin_amdgcn_mfma_f32_16x16x32_bf16(a1, b1, acc[1][1], 0, 0, 0);
        }
    }

    float* Mo = Mp + (size_t)(mat * 2 + split) * C * C;
#pragma unroll
    for (int i = 0; i < 2; ++i)
#pragma unroll
        for (int j = 0; j < 2; ++j)
#pragma unroll
            for (int r = 0; r < 4; ++r) {
                int row = rt * 64 + 32 * (w >> 1) + 16 * i + quad * 4 + r;
                int cc = ct * 64 + 32 * (w & 1) + 16 * j + col;
                Mo[(size_t)row * C + cc] = acc[i][j][r];
            }
}

// ---------- reduce Mp splits -> M (mats 0..3) ----------
__global__ __launch_bounds__(256) void reduce_mp(const float* __restrict__ Mp,
                                                 float* __restrict__ M) {
    int mat = blockIdx.y;
    int i = blockIdx.x * 256 + threadIdx.x;            // float4 index, 0..147455
    const float4* a = (const float4*)(Mp + (size_t)(mat * 2) * C * C);
    const float4* bb = (const float4*)(Mp + (size_t)(mat * 2 + 1) * C * C);
    float4* o = (float4*)(M + (size_t)mat * C * C);
    float4 va = a[i], vb = bb[i];
    float4 r = {va.x + vb.x, va.y + vb.y, va.z + vb.z, va.w + vb.w};
    o[i] = r;
}

// ---------- fp32 X^T X for pooled mats (4,5), n=64 ----------
__global__ __launch_bounds__(256) void ata_pooled(const float* __restrict__ p1,
                                                  const float* __restrict__ p2,
                                                  float* __restrict__ M) {
    int mat = 4 + blockIdx.z;
    const float* X = (mat == 4) ? p1 : p2;
    int n = B;
    float* Mo = M + (size_t)mat * C * C;
    int ct = blockIdx.x, rt = blockIdx.y;

    __shared__ float As[16][64];
    __shared__ float Bs[16][64];
    int tid = threadIdx.x;
    int tx = tid & 15, ty = tid >> 4;
    int lr = tid >> 4, lc = (tid & 15) * 4;

    float acc[4][4] = {};
    for (int k0 = 0; k0 < n; k0 += 16) {
        float4 av = *(const float4*)&X[(size_t)(k0 + lr) * C + rt * 64 + lc];
        float4 bv = *(const float4*)&X[(size_t)(k0 + lr) * C + ct * 64 + lc];
        __syncthreads();
        *(float4*)&As[lr][lc] = av;
        *(float4*)&Bs[lr][lc] = bv;
        __syncthreads();
#pragma unroll
        for (int kk = 0; kk < 16; ++kk) {
            float4 af = *(const float4*)&As[kk][ty * 4];
            float4 bf = *(const float4*)&Bs[kk][tx * 4];
            float a[4] = {af.x, af.y, af.z, af.w};
            float bb[4] = {bf.x, bf.y, bf.z, bf.w};
#pragma unroll
            for (int i = 0; i < 4; ++i)
#pragma unroll
                for (int j = 0; j < 4; ++j)
                    acc[i][j] = fmaf(a[i], bb[j], acc[i][j]);
        }
    }
#pragma unroll
    for (int i = 0; i < 4; ++i) {
        float4 o = {acc[i][0], acc[i][1], acc[i][2], acc[i][3]};
        *(float4*)&Mo[(size_t)(rt * 64 + ty * 4 + i) * C + ct * 64 + tx * 4] = o;
    }
}

// ---------- colsum for mats 0..3 from XgT (no atomics) ----------
__global__ __launch_bounds__(256) void colsum4_kernel(const ushort* __restrict__ XgT,
                                                      float* __restrict__ colsum) {
    int mat = blockIdx.y, cb = blockIdx.x * 4;
    int r = threadIdx.x >> 6, lane = threadIdx.x & 63;
    const ushort* row = XgT + ((size_t)mat * C + cb + r) * NLOC;
    float s = 0.f;
    for (int i = lane; i < NLOC; i += 64) s += bf2f(row[i]);
    for (int off = 32; off > 0; off >>= 1) s += __shfl_down(s, off, 64);
    if (lane == 0) colsum[mat * C + cb + r] = s;
}

// ---------- colsum pooled (no atomics): 6 blocks ----------
__global__ __launch_bounds__(256) void colsum_pooled(const float* __restrict__ p1,
                                                     const float* __restrict__ p2,
                                                     float* __restrict__ colsum) {
    int mat = 4 + blockIdx.y;
    const float* X = (mat == 4) ? p1 : p2;
    int c = blockIdx.x * 256 + threadIdx.x;
    float s = 0.f;
    for (int r = 0; r < B; ++r) s += X[(size_t)r * C + c];
    colsum[mat * C + c] = s;
}

// ---------- std term ----------
__global__ __launch_bounds__(256) void std_kernel(const float* __restrict__ M,
                                                  const float* __restrict__ colsum,
                                                  float* __restrict__ slots) {
    int mat = blockIdx.y;
    float n = (mat < 4) ? (float)NLOC : (float)B;
    int c = blockIdx.x * 256 + threadIdx.x;
    float r = 0.f;
    if (c < C) {
        float mcc = M[(size_t)mat * C * C + (size_t)c * C + c];
        float cs = colsum[mat * C + c];
        float var = (mcc - cs * cs / n) / (n - 1.0f);
        float sd = sqrtf(var + 1e-5f);
        float g = 1.0f - sd;
        r = g > 0.f ? g : 0.f;
    }
    __shared__ float s4[4];
    float t = blk_reduce_sum(r, s4);
    if (threadIdx.x == 0) atomicAdd(&slots[SLOT_STD + mat], t);
}

// ---------- cov term: grid-stride, 48 blocks x 16 rows per mat ----------
__global__ __launch_bounds__(256) void cov_kernel(const float* __restrict__ M,
                                                  const float* __restrict__ colsum,
                                                  float* __restrict__ slots) {
    int mat = blockIdx.y;
    float n = (mat < 4) ? (float)NLOC : (float)B;
    float invn1 = 1.0f / (n - 1.0f);
    const float* Mm = M + (size_t)mat * C * C;
    __shared__ float cs_s[C];
    for (int c = threadIdx.x; c < C; c += 256) cs_s[c] = colsum[mat * C + c];
    __syncthreads();
    float s = 0.f;
    int r0 = blockIdx.x * 16;
    for (int r = 0; r < 16; ++r) {
        int row = r0 + r;
        float csr = cs_s[row] / n;
        const float* Mr = Mm + (size_t)row * C;
        for (int c = threadIdx.x; c < C; c += 256) {
            float cv = (Mr[c] - csr * cs_s[c]) * invn1;
            if (c != row) s = fmaf(cv, cv, s);
        }
    }
    __shared__ float s4[4];
    float t = blk_reduce_sum(s, s4);
    if (threadIdx.x == 0) atomicAdd(&slots[SLOT_COV + mat], t);
}

// ---------- invariance terms ----------
__global__ __launch_bounds__(256) void inv_global_kernel(const float* __restrict__ p1,
                                                         const float* __restrict__ p2,
                                                         float* __restrict__ slots) {
    int idx = blockIdx.x * 256 + threadIdx.x;
    int stride = gridDim.x * 256;
    float s = 0.f;
    for (int i = idx; i < B * C; i += stride) {
        float d = p1[i] - p2[i];
        s = fmaf(d, d, s);
    }
    __shared__ float s4[4];
    float t = blk_reduce_sum(s, s4);
    if (threadIdx.x == 0) atomicAdd(&slots[SLOT_INVG], t);
}

__global__ __launch_bounds__(256) void inv_local2(const ushort* __restrict__ XgT,
                                                  float* __restrict__ slots) {
    int pair = blockIdx.y;
    const uint* A4 = (const uint*)(XgT + (size_t)(2 * pair) * C * NLOC);
    const uint* B4 = (const uint*)(XgT + (size_t)(2 * pair + 1) * C * NLOC);
    int idx = blockIdx.x * 256 + threadIdx.x;
    int stride = gridDim.x * 256;
    int n = C * NLOC / 2;
    float s = 0.f;
    for (int i = idx; i < n; i += stride) {
        uint ua = A4[i], ub = B4[i];
        float d0 = bf2f_lo(ua) - bf2f_lo(ub);
        float d1 = bf2f_hi(ua) - bf2f_hi(ub);
        s = fmaf(d0, d0, s);
        s = fmaf(d1, d1, s);
    }
    __shared__ float s4[4];
    float t = blk_reduce_sum(s, s4);
    if (threadIdx.x == 0) atomicAdd(&slots[(pair == 0) ? SLOT_INV1 : SLOT_INV2], t);
}

// ---------- final combine ----------
__global__ void final_kernel(const float* __restrict__ slots, float* __restrict__ out) {
    float std_t[6], cov_t[6];
    for (int m = 0; m < 6; ++m) {
        std_t[m] = slots[SLOT_STD + m] / (float)C * 0.5f;
        cov_t[m] = slots[SLOT_COV + m] / (float)C;
    }
    float inv_g = slots[SLOT_INVG] / (float)(B * C);
    float global_loss = 25.0f * inv_g + 25.0f * (std_t[4] + std_t[5]) + (cov_t[4] + cov_t[5]);
    float inv1 = 25.0f * slots[SLOT_INV1] / (float)(NLOC * C);
    float inv2 = 25.0f * slots[SLOT_INV2] / (float)(NLOC * C);
    float var1 = 25.0f * (std_t[0] + std_t[1]);
    float var2 = 25.0f * (std_t[2] + std_t[3]);
    float cov1 = cov_t[0] + cov_t[1];
    float cov2 = cov_t[2] + cov_t[3];
    float local_loss = (inv1 + inv2) * 0.5f + (var1 + var2) * 0.5f + (cov1 + cov2) * 0.5f;
    out[0] = 0.5f * global_loss + 0.5f * local_loss;
}

extern "C" void kernel_launch(void* const* d_in, const int* in_sizes, int n_in,
                              void* d_out, int out_size, void* d_ws, size_t ws_size,
                              hipStream_t stream) {
    const float* spatial_1 = (const float*)d_in[0];
    const float* pooled_1  = (const float*)d_in[1];
    const float* spatial_2 = (const float*)d_in[2];
    const float* pooled_2  = (const float*)d_in[3];
    float* out = (float*)d_out;

    char* ws = (char*)d_ws;
    float*  slots  = (float*)(ws + OFF_SLOTS);
    float*  colsum = (float*)(ws + OFF_COLSUM);
    ull*    nn1    = (ull*)(ws + OFF_NN1);
    ull*    nn2    = (ull*)(ws + OFF_NN2);
    int*    sel_p  = (int*)(ws + OFF_SELP);
    int*    sel_q  = (int*)(ws + OFF_SELQ);
    float*  norm   = (float*)(ws + OFF_NORM);
    ushort* xT     = (ushort*)(ws + OFF_XT);
    float*  Mp     = (float*)(ws + OFF_MP);   // overlays xT (dead after gather_t)
    ushort* XgT    = (ushort*)(ws + OFF_XGT);
    float*  M      = (float*)(ws + OFF_M);

    hipMemsetAsync(ws, 0, OFF_NN1, stream);                         // slots + colsum
    hipMemsetAsync(ws + OFF_NN1, 0xFF, OFF_SELP - OFF_NN1, stream); // nn keys

    convert_kernel<<<dim3(9, 12, 128), 256, 0, stream>>>(spatial_1, spatial_2, xT);
    norm_kernel2<<<dim3(9, B, 2), 256, 0, stream>>>(xT, norm);
    cdist_mfma<<<dim3(9, 5, B), 256, 0, stream>>>(xT, norm, nn1, nn2);
    select_topk_wave<<<dim3(B, 2), 64, 0, stream>>>(nn1, nn2, sel_p, sel_q);
    gather_t<<<dim3(B, 4), 256, 0, stream>>>(xT, sel_p, sel_q, XgT);
    ata_mfma<<<dim3(12, 12, 8), 256, 0, stream>>>(XgT, Mp);
    ata_pooled<<<dim3(12, 12, 2), 256, 0, stream>>>(pooled_1, pooled_2, M);
    reduce_mp<<<dim3(576, 4), 256, 0, stream>>>(Mp, M);
    colsum4_kernel<<<dim3(192, 4), 256, 0, stream>>>(XgT, colsum);
    colsum_pooled<<<dim3(3, 2), 256, 0, stream>>>(pooled_1, pooled_2, colsum);
    std_kernel<<<dim3(3, 6), 256, 0, stream>>>(M, colsum, slots);
    cov_kernel<<<dim3(48, 6), 256, 0, stream>>>(M, colsum, slots);
    inv_global_kernel<<<dim3(96), 256, 0, stream>>>(pooled_1, pooled_2, slots);
    inv_local2<<<dim3(300, 2), 256, 0, stream>>>(XgT, slots);
    final_kernel<<<1, 1, 0, stream>>>(slots, out);
}

// Round 4
// 487.466 us; speedup vs baseline: 2.8427x; 1.1333x over previous
//
#include <hip/hip_runtime.h>
#include <stdint.h>

typedef unsigned long long ull;
typedef unsigned int uint;
typedef unsigned short ushort;

typedef __attribute__((ext_vector_type(8))) short short8;
typedef __attribute__((ext_vector_type(4))) float floatx4;

#define B   64
#define C   768
#define HW  576
#define K   50
#define NLOC (B*K)          // 3200

// ---- workspace layout (bytes) ----
#define OFF_SLOTS   0            // 64 floats
#define OFF_COLSUM  256          // 6*768*4 = 18432
#define OFF_NN1     18688        // 64*576*8 = 294912
#define OFF_NN2     313600       // 294912
#define OFF_SELP    608512       // 2*64*50*4 = 25600
#define OFF_SELQ    634112       // 25600
#define OFF_NORM    659712       // 2*64*576*4 = 294912
#define OFF_XT      954624       // 2*64*576*768*2 = 113246208  (dead after gather -> reused as Mp)
#define OFF_MP      OFF_XT       // 4 mats * 5 splits * 768*768*4 = 47185920 (fits in XT region)
#define OFF_XGT     114200832    // 4*768*3200*2 = 19660800
#define OFF_M       133861632    // 6*768*768*4 = 14155776
// total 148017408

#define SLOT_INVG 0
#define SLOT_STD  1   // +mat (0..5)
#define SLOT_COV  7   // +mat (0..5)
#define SLOT_INV1 13
#define SLOT_INV2 14

__device__ __forceinline__ ull umin64(ull a, ull b) { return a < b ? a : b; }

__device__ __forceinline__ float bf2f_lo(uint u) { return __uint_as_float(u << 16); }
__device__ __forceinline__ float bf2f_hi(uint u) { return __uint_as_float(u & 0xffff0000u); }
__device__ __forceinline__ float bf2f(ushort u) { return __uint_as_float(((uint)u) << 16); }

__device__ __forceinline__ ushort f2bf(float f) {
    uint u = __float_as_uint(f);
    uint r = (u + 0x7fffu + ((u >> 16) & 1u)) >> 16;   // RNE
    return (ushort)r;
}

__device__ __forceinline__ float blk_reduce_sum(float v, float* s4) {
    for (int off = 32; off > 0; off >>= 1) v += __shfl_down(v, off, 64);
    int lane = threadIdx.x & 63, w = threadIdx.x >> 6;
    if (lane == 0) s4[w] = v;
    __syncthreads();
    float r = 0.f;
    if (threadIdx.x == 0) r = s4[0] + s4[1] + s4[2] + s4[3];
    return r;
}

// ---------- convert fp32 [b][c][p] -> bf16 xT[which][b][p][c] + fused norms ----------
__global__ __launch_bounds__(256) void convert_kernel(const float* __restrict__ x1,
                                                      const float* __restrict__ x2,
                                                      ushort* __restrict__ xT,
                                                      float* __restrict__ norm) {
    int z = blockIdx.z;
    int which = z >> 6, b = z & 63;
    const float* X = which ? x2 : x1;
    int p0 = blockIdx.x * 64, c0 = blockIdx.y * 64;
    __shared__ float tile[64][65];
    const float* src = X + ((size_t)b * C + c0) * HW + p0;
    int col = threadIdx.x & 63, r0 = threadIdx.x >> 6;
    for (int rr = r0; rr < 64; rr += 4)
        tile[rr][col] = src[(size_t)rr * HW + col];
    __syncthreads();
    ushort* dst = xT + (((size_t)which * B + b) * HW + p0) * C + c0;
    int cc = (threadIdx.x & 31) * 2, pr0 = threadIdx.x >> 5;
    for (int pr = pr0; pr < 64; pr += 8) {
        ushort2 o;
        o.x = f2bf(tile[cc][pr]);
        o.y = f2bf(tile[cc + 1][pr]);
        *(ushort2*)&dst[(size_t)pr * C + cc] = o;
    }
    // fused partial norms (squares of bf16-rounded values, consistent with Gram)
    int p = threadIdx.x >> 2, g = threadIdx.x & 3;
    float s = 0.f;
    for (int c = g * 16; c < g * 16 + 16; ++c) {
        float v = bf2f(f2bf(tile[c][p]));
        s = fmaf(v, v, s);
    }
    s += __shfl_down(s, 2, 4);
    s += __shfl_down(s, 1, 4);
    if (g == 0) atomicAdd(&norm[((size_t)which * B + b) * HW + p0 + p], s);
}

// ---------- cdist Gram via MFMA, 128x128 tile, XCD-swizzled 1-D grid ----------
__global__ __launch_bounds__(256) void cdist_mfma(const ushort* __restrict__ xT,
                                                  const float* __restrict__ norm,
                                                  ull* __restrict__ nn1,
                                                  ull* __restrict__ nn2) {
    int id = blockIdx.x;
    int xcd = id & 7, slot = id >> 3;
    int b = xcd + 8 * (slot / 25);      // all 25 tiles of a batch share one XCD slot
    int t = slot % 25;
    int qt = t % 5, pt = t / 5;

    const ushort* X1 = xT + (size_t)b * HW * C;
    const ushort* X2 = xT + (size_t)(B + b) * HW * C;

    __shared__ ull pool[4224];          // 33792 B: A(16384)+B(16384); red overlays
    char* As = (char*)pool;
    char* Bs = As + 16384;

    int tid = threadIdx.x;
    int w = tid >> 6, l = tid & 63;
    int quad = l >> 4, col = l & 15;
    int lrow = l >> 2, pos = l & 3;

    const ushort* gA[2][2]; const ushort* gB[2][2];
    char* dA[2][2]; char* dB[2][2];
#pragma unroll
    for (int n = 0; n < 2; ++n) {
        int sm = w * 32 + n * 16 + lrow;            // LDS row 0..127
        int cdat = pos ^ ((sm >> 1) & 3);
        int p = pt * 128 + sm; if (p >= HW) p = HW - 1;
        int q = qt * 128 + sm; if (q >= HW) q = HW - 1;
#pragma unroll
        for (int s = 0; s < 2; ++s) {
            gA[s][n] = X1 + (size_t)p * C + s * 32 + cdat * 8;
            gB[s][n] = X2 + (size_t)q * C + s * 32 + cdat * 8;
            dA[s][n] = As + s * 8192 + w * 2048 + n * 1024;
            dB[s][n] = Bs + s * 8192 + w * 2048 + n * 1024;
        }
    }

    int offA[4], offB[4];
#pragma unroll
    for (int i = 0; i < 4; ++i) {
        int m_loc = (w >> 1) * 64 + i * 16 + col;
        offA[i] = m_loc * 64 + ((quad ^ ((m_loc >> 1) & 3)) * 16);
        int n_loc = (w & 1) * 64 + i * 16 + col;
        offB[i] = n_loc * 64 + ((quad ^ ((n_loc >> 1) & 3)) * 16);
    }

    floatx4 zero = {0.f, 0.f, 0.f, 0.f};
    floatx4 acc[4][4];
#pragma unroll
    for (int i = 0; i < 4; ++i)
#pragma unroll
        for (int j = 0; j < 4; ++j) acc[i][j] = zero;

    for (int k0 = 0; k0 < C; k0 += 64) {
        __syncthreads();
#pragma unroll
        for (int s = 0; s < 2; ++s)
#pragma unroll
            for (int n = 0; n < 2; ++n) {
                __builtin_amdgcn_global_load_lds(
                    (const __attribute__((address_space(1))) void*)(gA[s][n] + k0),
                    (__attribute__((address_space(3))) void*)dA[s][n], 16, 0, 0);
                __builtin_amdgcn_global_load_lds(
                    (const __attribute__((address_space(1))) void*)(gB[s][n] + k0),
                    (__attribute__((address_space(3))) void*)dB[s][n], 16, 0, 0);
            }
        __syncthreads();
#pragma unroll
        for (int s = 0; s < 2; ++s) {
            short8 a[4], bb[4];
#pragma unroll
            for (int i = 0; i < 4; ++i) a[i] = *(const short8*)(As + s * 8192 + offA[i]);
#pragma unroll
            for (int j = 0; j < 4; ++j) bb[j] = *(const short8*)(Bs + s * 8192 + offB[j]);
#pragma unroll
            for (int i = 0; i < 4; ++i)
#pragma unroll
                for (int j = 0; j < 4; ++j)
                    acc[i][j] = __builtin_amdgcn_mfma_f32_16x16x32_bf16(a[i], bb[j], acc[i][j], 0, 0, 0);
        }
    }

    const float* n1g = norm + (size_t)b * HW;
    const float* n2g = norm + (size_t)(B + b) * HW;
    float n1v[4][4]; bool vp[4][4];
    float n2v[4];    bool vq[4];
#pragma unroll
    for (int i = 0; i < 4; ++i)
#pragma unroll
        for (int r = 0; r < 4; ++r) {
            int p = pt * 128 + (w >> 1) * 64 + i * 16 + quad * 4 + r;
            vp[i][r] = (p < HW);
            n1v[i][r] = n1g[p < HW ? p : (HW - 1)];
        }
#pragma unroll
    for (int j = 0; j < 4; ++j) {
        int q = qt * 128 + (w & 1) * 64 + j * 16 + col;
        vq[j] = (q < HW);
        n2v[j] = n2g[q < HW ? q : (HW - 1)];
    }

    __syncthreads();
    typedef ull row33[33];
    row33* red = (row33*)pool;

    // pass 1: per-p min over q
#pragma unroll
    for (int i = 0; i < 4; ++i)
#pragma unroll
        for (int r = 0; r < 4; ++r) {
            int p_loc = (w >> 1) * 64 + i * 16 + quad * 4 + r;
            ull best = ~0ull;
#pragma unroll
            for (int j = 0; j < 4; ++j) {
                if (!vq[j]) continue;
                float d2 = fmaxf(n1v[i][r] + n2v[j] - 2.0f * acc[i][j][r], 0.0f);
                unsigned q_glob = qt * 128 + (w & 1) * 64 + j * 16 + col;
                best = umin64(best, ((ull)__float_as_uint(d2) << 32) | q_glob);
            }
            red[p_loc][(w & 1) * 16 + col] = best;
        }
    __syncthreads();
    if (tid < 128) {
        int p_glob = pt * 128 + tid;
        ull m = ~0ull;
#pragma unroll
        for (int x = 0; x < 32; ++x) m = umin64(m, red[tid][x]);
        if (p_glob < HW) atomicMin(&nn1[(size_t)b * HW + p_glob], m);
    }
    __syncthreads();
    // pass 2: per-q min over p
#pragma unroll
    for (int j = 0; j < 4; ++j) {
        int q_loc = (w & 1) * 64 + j * 16 + col;
        ull best = ~0ull;
#pragma unroll
        for (int i = 0; i < 4; ++i)
#pragma unroll
            for (int r = 0; r < 4; ++r) {
                if (!vp[i][r]) continue;
                float d2 = fmaxf(n1v[i][r] + n2v[j] - 2.0f * acc[i][j][r], 0.0f);
                unsigned p_glob = pt * 128 + (w >> 1) * 64 + i * 16 + quad * 4 + r;
                best = umin64(best, ((ull)__float_as_uint(d2) << 32) | p_glob);
            }
        red[q_loc][(w >> 1) * 4 + quad] = best;
    }
    __syncthreads();
    if (tid < 128) {
        int q_glob = qt * 128 + tid;
        ull m = ~0ull;
#pragma unroll
        for (int x = 0; x < 8; ++x) m = umin64(m, red[tid][x]);
        if (q_glob < HW) atomicMin(&nn2[(size_t)b * HW + q_glob], m);
    }
}

// ---------- top-k: one wave per (b,dir), keys in registers ----------
__global__ __launch_bounds__(64) void select_topk_wave(const ull* __restrict__ nn1,
                                                       const ull* __restrict__ nn2,
                                                       int* __restrict__ sel_p,
                                                       int* __restrict__ sel_q) {
    int b = blockIdx.x, dir = blockIdx.y;
    const ull* nn = dir ? nn2 : nn1;
    int lane = threadIdx.x;
    ull key[9]; uint qv[9];
#pragma unroll
    for (int r = 0; r < 9; ++r) {
        int p = r * 64 + lane;
        ull e = nn[(size_t)b * HW + p];
        key[r] = (e & 0xFFFFFFFF00000000ull) | (unsigned)p;
        qv[r] = (uint)(e & 0xFFFFFFFFu);
    }
    int* sp = sel_p + (dir * B + b) * K;
    int* sq = sel_q + (dir * B + b) * K;
    for (int it = 0; it < K; ++it) {
        ull m = key[0];
#pragma unroll
        for (int r = 1; r < 9; ++r) m = umin64(m, key[r]);
#pragma unroll
        for (int off = 32; off > 0; off >>= 1) m = umin64(m, __shfl_xor(m, off, 64));
#pragma unroll
        for (int r = 0; r < 9; ++r) {
            if (key[r] == m) {
                sp[it] = (int)(uint)(m & 0xFFFFFFFFu);
                sq[it] = (int)qv[r];
                key[r] = ~0ull;
            }
        }
    }
}

// ---------- gather into XgT[s][c][i], i = j*64 + b (coalesced writes) ----------
// s: 0=x1[sel_p d0] 1=x2[sel_q d0] 2=x2[sel_p d1] 3=x1[sel_q d1]
__global__ __launch_bounds__(256) void gather_jmajor(const ushort* __restrict__ xT,
                                                     const int* __restrict__ sel_p,
                                                     const int* __restrict__ sel_q,
                                                     ushort* __restrict__ XgT) {
    int j = blockIdx.x, s = blockIdx.y;
    int dir = s >> 1;
    int whichsrc = (s == 1 || s == 2) ? 1 : 0;
    const int* sel = (s & 1) ? sel_q : sel_p;
    __shared__ int sidx[64];
    __shared__ uint buf[64][33];
    int tid = threadIdx.x;
    if (tid < 64) sidx[tid] = sel[(dir * B + tid) * K + j];
    __syncthreads();
    int rb = tid >> 2, u = tid & 3;     // read mapping: row rb, quarter u
    const ushort* srow = xT + (((size_t)whichsrc * B + rb) * HW + sidx[rb]) * C;
    int wv = tid >> 6, lb = tid & 63;   // write mapping: lane = b
    ushort* obase = XgT + (size_t)s * C * NLOC + (size_t)j * 64 + lb;
    for (int ch = 0; ch < 12; ++ch) {
        __syncthreads();
        uint4 v0 = *(const uint4*)(srow + ch * 64 + u * 8);
        uint4 v1 = *(const uint4*)(srow + ch * 64 + (u + 4) * 8);
        buf[rb][u * 4 + 0] = v0.x; buf[rb][u * 4 + 1] = v0.y;
        buf[rb][u * 4 + 2] = v0.z; buf[rb][u * 4 + 3] = v0.w;
        buf[rb][(u + 4) * 4 + 0] = v1.x; buf[rb][(u + 4) * 4 + 1] = v1.y;
        buf[rb][(u + 4) * 4 + 2] = v1.z; buf[rb][(u + 4) * 4 + 3] = v1.w;
        __syncthreads();
#pragma unroll
        for (int st = 0; st < 16; ++st) {
            int cl = wv + st * 4;
            uint uv = buf[lb][cl >> 1];
            ushort val = (cl & 1) ? (ushort)(uv >> 16) : (ushort)(uv & 0xffffu);
            obase[(size_t)(ch * 64 + cl) * NLOC] = val;
        }
    }
}

// ---------- Mp[mat][split] = partial X^T X via MFMA, 128x128 tile, split-K=5 ----------
__global__ __launch_bounds__(256) void ata_mfma(const ushort* __restrict__ XgT,
                                                float* __restrict__ Mp) {
    int bx = blockIdx.x;                 // 0..35
    int mat = blockIdx.y, split = blockIdx.z;
    int rt = bx / 6, ct = bx % 6;
    const ushort* X = XgT + (size_t)mat * C * NLOC;

    __shared__ ull pool[4096];           // 32768 B
    char* As = (char*)pool;
    char* Bs = As + 16384;

    int tid = threadIdx.x;
    int w = tid >> 6, l = tid & 63;
    int quad = l >> 4, col = l & 15;
    int lrow = l >> 2, pos = l & 3;

    const ushort* gA[2][2]; const ushort* gB[2][2];
    char* dA[2][2]; char* dB[2][2];
#pragma unroll
    for (int n = 0; n < 2; ++n) {
        int sm = w * 32 + n * 16 + lrow;
        int cdat = pos ^ ((sm >> 1) & 3);
#pragma unroll
        for (int s = 0; s < 2; ++s) {
            gA[s][n] = X + (size_t)(rt * 128 + sm) * NLOC + split * 640 + s * 32 + cdat * 8;
            gB[s][n] = X + (size_t)(ct * 128 + sm) * NLOC + split * 640 + s * 32 + cdat * 8;
            dA[s][n] = As + s * 8192 + w * 2048 + n * 1024;
            dB[s][n] = Bs + s * 8192 + w * 2048 + n * 1024;
        }
    }

    int offA[4], offB[4];
#pragma unroll
    for (int i = 0; i < 4; ++i) {
        int m_loc = (w >> 1) * 64 + i * 16 + col;
        offA[i] = m_loc * 64 + ((quad ^ ((m_loc >> 1) & 3)) * 16);
        int n_loc = (w & 1) * 64 + i * 16 + col;
        offB[i] = n_loc * 64 + ((quad ^ ((n_loc >> 1) & 3)) * 16);
    }

    floatx4 zero = {0.f, 0.f, 0.f, 0.f};
    floatx4 acc[4][4];
#pragma unroll
    for (int i = 0; i < 4; ++i)
#pragma unroll
        for (int j = 0; j < 4; ++j) acc[i][j] = zero;

    for (int k0 = 0; k0 < 640; k0 += 64) {
        __syncthreads();
#pragma unroll
        for (int s = 0; s < 2; ++s)
#pragma unroll
            for (int n = 0; n < 2; ++n) {
                __builtin_amdgcn_global_load_lds(
                    (const __attribute__((address_space(1))) void*)(gA[s][n] + k0),
                    (__attribute__((address_space(3))) void*)dA[s][n], 16, 0, 0);
                __builtin_amdgcn_global_load_lds(
                    (const __attribute__((address_space(1))) void*)(gB[s][n] + k0),
                    (__attribute__((address_space(3))) void*)dB[s][n], 16, 0, 0);
            }
        __syncthreads();
#pragma unroll
        for (int s = 0; s < 2; ++s) {
            short8 a[4], bb[4];
#pragma unroll
            for (int i = 0; i < 4; ++i) a[i] = *(const short8*)(As + s * 8192 + offA[i]);
#pragma unroll
            for (int j = 0; j < 4; ++j) bb[j] = *(const short8*)(Bs + s * 8192 + offB[j]);
#pragma unroll
            for (int i = 0; i < 4; ++i)
#pragma unroll
                for (int j = 0; j < 4; ++j)
                    acc[i][j] = __builtin_amdgcn_mfma_f32_16x16x32_bf16(a[i], bb[j], acc[i][j], 0, 0, 0);
        }
    }

    float* Mo = Mp + (size_t)(mat * 5 + split) * C * C;
#pragma unroll
    for (int i = 0; i < 4; ++i)
#pragma unroll
        for (int j = 0; j < 4; ++j)
#pragma unroll
            for (int r = 0; r < 4; ++r) {
                int row = rt * 128 + (w >> 1) * 64 + i * 16 + quad * 4 + r;
                int cc  = ct * 128 + (w & 1) * 64 + j * 16 + col;
                Mo[(size_t)row * C + cc] = acc[i][j][r];
            }
}

// ---------- reduce Mp splits -> M (mats 0..3) ----------
__global__ __launch_bounds__(256) void reduce_mp(const float* __restrict__ Mp,
                                                 float* __restrict__ M) {
    int mat = blockIdx.y;
    int i = blockIdx.x * 256 + threadIdx.x;            // float4 index, 0..147455
    float4 r = {0.f, 0.f, 0.f, 0.f};
#pragma unroll
    for (int s = 0; s < 5; ++s) {
        const float4* a = (const float4*)(Mp + (size_t)(mat * 5 + s) * C * C);
        float4 v = a[i];
        r.x += v.x; r.y += v.y; r.z += v.z; r.w += v.w;
    }
    ((float4*)(M + (size_t)mat * C * C))[i] = r;
}

// ---------- fp32 X^T X for pooled mats (4,5), n=64 ----------
__global__ __launch_bounds__(256) void ata_pooled(const float* __restrict__ p1,
                                                  const float* __restrict__ p2,
                                                  float* __restrict__ M) {
    int mat = 4 + blockIdx.z;
    const float* X = (mat == 4) ? p1 : p2;
    int n = B;
    float* Mo = M + (size_t)mat * C * C;
    int ct = blockIdx.x, rt = blockIdx.y;

    __shared__ float As[16][64];
    __shared__ float Bs[16][64];
    int tid = threadIdx.x;
    int tx = tid & 15, ty = tid >> 4;
    int lr = tid >> 4, lc = (tid & 15) * 4;

    float acc[4][4] = {};
    for (int k0 = 0; k0 < n; k0 += 16) {
        float4 av = *(const float4*)&X[(size_t)(k0 + lr) * C + rt * 64 + lc];
        float4 bv = *(const float4*)&X[(size_t)(k0 + lr) * C + ct * 64 + lc];
        __syncthreads();
        *(float4*)&As[lr][lc] = av;
        *(float4*)&Bs[lr][lc] = bv;
        __syncthreads();
#pragma unroll
        for (int kk = 0; kk < 16; ++kk) {
            float4 af = *(const float4*)&As[kk][ty * 4];
            float4 bf = *(const float4*)&Bs[kk][tx * 4];
            float a[4] = {af.x, af.y, af.z, af.w};
            float bb[4] = {bf.x, bf.y, bf.z, bf.w};
#pragma unroll
            for (int i = 0; i < 4; ++i)
#pragma unroll
                for (int j = 0; j < 4; ++j)
                    acc[i][j] = fmaf(a[i], bb[j], acc[i][j]);
        }
    }
#pragma unroll
    for (int i = 0; i < 4; ++i) {
        float4 o = {acc[i][0], acc[i][1], acc[i][2], acc[i][3]};
        *(float4*)&Mo[(size_t)(rt * 64 + ty * 4 + i) * C + ct * 64 + tx * 4] = o;
    }
}

// ---------- colsum for mats 0..3 from XgT (no atomics) ----------
__global__ __launch_bounds__(256) void colsum4_kernel(const ushort* __restrict__ XgT,
                                                      float* __restrict__ colsum) {
    int mat = blockIdx.y, cb = blockIdx.x * 4;
    int r = threadIdx.x >> 6, lane = threadIdx.x & 63;
    const ushort* row = XgT + ((size_t)mat * C + cb + r) * NLOC;
    float s = 0.f;
    for (int i = lane; i < NLOC; i += 64) s += bf2f(row[i]);
    for (int off = 32; off > 0; off >>= 1) s += __shfl_down(s, off, 64);
    if (lane == 0) colsum[mat * C + cb + r] = s;
}

// ---------- colsum pooled (no atomics) ----------
__global__ __launch_bounds__(256) void colsum_pooled(const float* __restrict__ p1,
                                                     const float* __restrict__ p2,
                                                     float* __restrict__ colsum) {
    int mat = 4 + blockIdx.y;
    const float* X = (mat == 4) ? p1 : p2;
    int c = blockIdx.x * 256 + threadIdx.x;
    float s = 0.f;
    for (int r = 0; r < B; ++r) s += X[(size_t)r * C + c];
    colsum[mat * C + c] = s;
}

// ---------- std term ----------
__global__ __launch_bounds__(256) void std_kernel(const float* __restrict__ M,
                                                  const float* __restrict__ colsum,
                                                  float* __restrict__ slots) {
    int mat = blockIdx.y;
    float n = (mat < 4) ? (float)NLOC : (float)B;
    int c = blockIdx.x * 256 + threadIdx.x;
    float r = 0.f;
    if (c < C) {
        float mcc = M[(size_t)mat * C * C + (size_t)c * C + c];
        float cs = colsum[mat * C + c];
        float var = (mcc - cs * cs / n) / (n - 1.0f);
        float sd = sqrtf(var + 1e-5f);
        float g = 1.0f - sd;
        r = g > 0.f ? g : 0.f;
    }
    __shared__ float s4[4];
    float t = blk_reduce_sum(r, s4);
    if (threadIdx.x == 0) atomicAdd(&slots[SLOT_STD + mat], t);
}

// ---------- cov term: 48 blocks x 16 rows per mat ----------
__global__ __launch_bounds__(256) void cov_kernel(const float* __restrict__ M,
                                                  const float* __restrict__ colsum,
                                                  float* __restrict__ slots) {
    int mat = blockIdx.y;
    float n = (mat < 4) ? (float)NLOC : (float)B;
    float invn1 = 1.0f / (n - 1.0f);
    const float* Mm = M + (size_t)mat * C * C;
    __shared__ float cs_s[C];
    for (int c = threadIdx.x; c < C; c += 256) cs_s[c] = colsum[mat * C + c];
    __syncthreads();
    float s = 0.f;
    int r0 = blockIdx.x * 16;
    for (int r = 0; r < 16; ++r) {
        int row = r0 + r;
        float csr = cs_s[row] / n;
        const float* Mr = Mm + (size_t)row * C;
        for (int c = threadIdx.x; c < C; c += 256) {
            float cv = (Mr[c] - csr * cs_s[c]) * invn1;
            if (c != row) s = fmaf(cv, cv, s);
        }
    }
    __shared__ float s4[4];
    float t = blk_reduce_sum(s, s4);
    if (threadIdx.x == 0) atomicAdd(&slots[SLOT_COV + mat], t);
}

// ---------- invariance terms ----------
__global__ __launch_bounds__(256) void inv_global_kernel(const float* __restrict__ p1,
                                                         const float* __restrict__ p2,
                                                         float* __restrict__ slots) {
    int idx = blockIdx.x * 256 + threadIdx.x;
    int stride = gridDim.x * 256;
    float s = 0.f;
    for (int i = idx; i < B * C; i += stride) {
        float d = p1[i] - p2[i];
        s = fmaf(d, d, s);
    }
    __shared__ float s4[4];
    float t = blk_reduce_sum(s, s4);
    if (threadIdx.x == 0) atomicAdd(&slots[SLOT_INVG], t);
}

__global__ __launch_bounds__(256) void inv_local2(const ushort* __restrict__ XgT,
                                                  float* __restrict__ slots) {
    int pair = blockIdx.y;
    const uint* A4 = (const uint*)(XgT + (size_t)(2 * pair) * C * NLOC);
    const uint* B4 = (const uint*)(XgT + (size_t)(2 * pair + 1) * C * NLOC);
    int idx = blockIdx.x * 256 + threadIdx.x;
    int stride = gridDim.x * 256;
    int n = C * NLOC / 2;
    float s = 0.f;
    for (int i = idx; i < n; i += stride) {
        uint ua = A4[i], ub = B4[i];
        float d0 = bf2f_lo(ua) - bf2f_lo(ub);
        float d1 = bf2f_hi(ua) - bf2f_hi(ub);
        s = fmaf(d0, d0, s);
        s = fmaf(d1, d1, s);
    }
    __shared__ float s4[4];
    float t = blk_reduce_sum(s, s4);
    if (threadIdx.x == 0) atomicAdd(&slots[(pair == 0) ? SLOT_INV1 : SLOT_INV2], t);
}

// ---------- final combine ----------
__global__ void final_kernel(const float* __restrict__ slots, float* __restrict__ out) {
    float std_t[6], cov_t[6];
    for (int m = 0; m < 6; ++m) {
        std_t[m] = slots[SLOT_STD + m] / (float)C * 0.5f;
        cov_t[m] = slots[SLOT_COV + m] / (float)C;
    }
    float inv_g = slots[SLOT_INVG] / (float)(B * C);
    float global_loss = 25.0f * inv_g + 25.0f * (std_t[4] + std_t[5]) + (cov_t[4] + cov_t[5]);
    float inv1 = 25.0f * slots[SLOT_INV1] / (float)(NLOC * C);
    float inv2 = 25.0f * slots[SLOT_INV2] / (float)(NLOC * C);
    float var1 = 25.0f * (std_t[0] + std_t[1]);
    float var2 = 25.0f * (std_t[2] + std_t[3]);
    float cov1 = cov_t[0] + cov_t[1];
    float cov2 = cov_t[2] + cov_t[3];
    float local_loss = (inv1 + inv2) * 0.5f + (var1 + var2) * 0.5f + (cov1 + cov2) * 0.5f;
    out[0] = 0.5f * global_loss + 0.5f * local_loss;
}

extern "C" void kernel_launch(void* const* d_in, const int* in_sizes, int n_in,
                              void* d_out, int out_size, void* d_ws, size_t ws_size,
                              hipStream_t stream) {
    const float* spatial_1 = (const float*)d_in[0];
    const float* pooled_1  = (const float*)d_in[1];
    const float* spatial_2 = (const float*)d_in[2];
    const float* pooled_2  = (const float*)d_in[3];
    float* out = (float*)d_out;

    char* ws = (char*)d_ws;
    float*  slots  = (float*)(ws + OFF_SLOTS);
    float*  colsum = (float*)(ws + OFF_COLSUM);
    ull*    nn1    = (ull*)(ws + OFF_NN1);
    ull*    nn2    = (ull*)(ws + OFF_NN2);
    int*    sel_p  = (int*)(ws + OFF_SELP);
    int*    sel_q  = (int*)(ws + OFF_SELQ);
    float*  norm   = (float*)(ws + OFF_NORM);
    ushort* xT     = (ushort*)(ws + OFF_XT);
    float*  Mp     = (float*)(ws + OFF_MP);   // overlays xT (dead after gather)
    ushort* XgT    = (ushort*)(ws + OFF_XGT);
    float*  M      = (float*)(ws + OFF_M);

    hipMemsetAsync(ws, 0, OFF_NN1, stream);                          // slots + colsum
    hipMemsetAsync(ws + OFF_NN1, 0xFF, OFF_SELP - OFF_NN1, stream);  // nn keys
    hipMemsetAsync(ws + OFF_NORM, 0, 294912, stream);                // norms (atomic accum)

    convert_kernel<<<dim3(9, 12, 128), 256, 0, stream>>>(spatial_1, spatial_2, xT, norm);
    cdist_mfma<<<1600, 256, 0, stream>>>(xT, norm, nn1, nn2);
    select_topk_wave<<<dim3(B, 2), 64, 0, stream>>>(nn1, nn2, sel_p, sel_q);
    gather_jmajor<<<dim3(K, 4), 256, 0, stream>>>(xT, sel_p, sel_q, XgT);
    ata_mfma<<<dim3(36, 4, 5), 256, 0, stream>>>(XgT, Mp);
    ata_pooled<<<dim3(12, 12, 2), 256, 0, stream>>>(pooled_1, pooled_2, M);
    reduce_mp<<<dim3(576, 4), 256, 0, stream>>>(Mp, M);
    colsum4_kernel<<<dim3(192, 4), 256, 0, stream>>>(XgT, colsum);
    colsum_pooled<<<dim3(3, 2), 256, 0, stream>>>(pooled_1, pooled_2, colsum);
    std_kernel<<<dim3(3, 6), 256, 0, stream>>>(M, colsum, slots);
    cov_kernel<<<dim3(48, 6), 256, 0, stream>>>(M, colsum, slots);
    inv_global_kernel<<<dim3(96), 256, 0, stream>>>(pooled_1, pooled_2, slots);
    inv_local2<<<dim3(300, 2), 256, 0, stream>>>(XgT, slots);
    final_kernel<<<1, 1, 0, stream>>>(slots, out);
}